// Round 14
// baseline (197.432 us; speedup 1.0000x reference)
//
#include <hip/hip_runtime.h>
#include <math.h>

typedef unsigned short u16;
typedef unsigned char  u8;
typedef unsigned int   u32;
typedef __attribute__((ext_vector_type(8))) short bf16x8;
typedef __attribute__((ext_vector_type(4))) float f32x4;

#define NSEQ   1024
#define DMODEL 1024
#define ZTOT   64
#define LOG2E  1.4426950408889634f

typedef const __attribute__((address_space(1))) void* gp1;
typedef __attribute__((address_space(3))) void* lp3;

__device__ __forceinline__ void gload16(const void* g, void* l) {
    __builtin_amdgcn_global_load_lds((gp1)g, (lp3)l, 16, 0, 0);
}

__device__ __forceinline__ u16 f2bf(float f) {
    u32 u = __builtin_bit_cast(u32, f);
    return (u16)((u + 0x7FFFu + ((u >> 16) & 1u)) >> 16);
}

__device__ __forceinline__ float bf2f(u32 lo16) {
    u32 t = lo16 << 16;
    return __builtin_bit_cast(float, t);
}

// HW packed f32->bf16 (RNE), 2 values -> 1 dword
__device__ __forceinline__ u32 cvt_pk_bf16(float a, float b) {
    u32 r;
    asm("v_cvt_pk_bf16_f32 %0, %1, %2" : "=v"(r) : "v"(a), "v"(b));
    return r;
}

// ---------------------------------------------------------------------------
// fp32 -> bf16 elementwise: x (4M elems) + 5 weights (1M each) in ONE launch.
// ---------------------------------------------------------------------------
struct P5 { const float* in[5]; u16* out[5]; };
__launch_bounds__(256)
__global__ void cvt_all(const float* __restrict__ x, u16* __restrict__ xb, P5 p) {
    int bid = blockIdx.x;
    const float* in;
    u16* out;
    int blk;
    if (bid < 4096) { in = x; out = xb; blk = bid; }
    else {
        int which = (bid - 4096) >> 10;
        blk = bid & 1023;
        in = p.in[which];
        out = p.out[which];
    }
    int i = (blk * 256 + threadIdx.x) * 4;
    float4 v = *(const float4*)(in + i);
    uint2 o;
    o.x = cvt_pk_bf16(v.x, v.y);
    o.y = cvt_pk_bf16(v.z, v.w);
    *(uint2*)(out + i) = o;
}

// sign(sum |row|) over 64 bf16 -> 0/1 ; grid 512: first half Kh->km, second Qh->qm
__launch_bounds__(256)
__global__ void rowmask2_bf(const u16* __restrict__ Kh, const u16* __restrict__ Qh,
                            float* __restrict__ km, float* __restrict__ qm) {
    int b = blockIdx.x;
    const u16* T = (b < 256) ? Kh : Qh;
    float* o = (b < 256) ? km : qm;
    int r = (b & 255) * 256 + threadIdx.x;
    const uint4* p = (const uint4*)(T + (size_t)r * 64);
    u32 acc = 0;
    #pragma unroll
    for (int i = 0; i < 8; i++) {
        uint4 q = p[i];
        acc |= (q.x | q.y | q.z | q.w) & 0x7fff7fffu;
    }
    o[r] = acc ? 1.f : 0.f;
}

// Vt[z][dh][tok] &= (km[z][tok] != 0)
__launch_bounds__(256)
__global__ void vt_km(u16* __restrict__ Vt, const float* __restrict__ km) {
    int idx = blockIdx.x * 256 + threadIdx.x;  // uint4 index (8 bf16)
    int e0 = idx * 8;
    int z = e0 >> 16;
    int tok = e0 & 1023;
    float4 ka = *(const float4*)(km + z * 1024 + tok);
    float4 kb = *(const float4*)(km + z * 1024 + tok + 4);
    uint4 v = *(uint4*)(Vt + e0);
    u32 m;
    m = (ka.x != 0.f ? 0x0000FFFFu : 0u) | (ka.y != 0.f ? 0xFFFF0000u : 0u); v.x &= m;
    m = (ka.z != 0.f ? 0x0000FFFFu : 0u) | (ka.w != 0.f ? 0xFFFF0000u : 0u); v.y &= m;
    m = (kb.x != 0.f ? 0x0000FFFFu : 0u) | (kb.y != 0.f ? 0xFFFF0000u : 0u); v.z &= m;
    m = (kb.z != 0.f ? 0x0000FFFFu : 0u) | (kb.w != 0.f ? 0xFFFF0000u : 0u); v.w &= m;
    *(uint4*)(Vt + e0) = v;
}

// ---------------------------------------------------------------------------
// Fused QKV projection GEMM, m97 structure: BM=BN=128, BK=32, 4 waves, 2-buf.
// grid (24, 32): bx>>3 selects {Q, K, V}.
// Q/K: swapped-operand MFMA -> channel on q-axis -> 8B packed head-major
// stores. V: token on q-axis -> 8B packed [z][dh][tok] stores.
// ---------------------------------------------------------------------------
__launch_bounds__(256)
__global__ void gemm_qkv(const u16* __restrict__ A,
                         const u16* __restrict__ Wq, const u16* __restrict__ Wk,
                         const u16* __restrict__ Wv,
                         u16* __restrict__ Qh, u16* __restrict__ Kh, u16* __restrict__ Vt)
{
    __shared__ __align__(16) u16 lA[2][128 * 32];
    __shared__ __align__(16) u16 lB[2][128 * 32];
    const int tid = threadIdx.x, lane = tid & 63, w = tid >> 6;
    const int frow = lane & 15, koct = lane >> 4;
    const int sel = blockIdx.x >> 3;
    const int col0 = (blockIdx.x & 7) * 128, row0 = blockIdx.y * 128;
    const u16* B = (sel == 0) ? Wq : (sel == 1) ? Wk : Wv;
    const int wrow = (w >> 1) * 64, wcol = (w & 1) * 64;
    f32x4 acc[4][4] = {};

    auto stage = [&](int buf, int k0) {
        #pragma unroll
        for (int i = 0; i < 2; i++) {
            int p = tid + i * 256;
            int row = p >> 2, sl = p & 3, ssl = sl ^ ((row >> 1) & 3);
            gload16(A + (size_t)(row0 + row) * 1024 + k0 + ssl * 8, (char*)lA[buf] + p * 16);
        }
        #pragma unroll
        for (int i = 0; i < 2; i++) {
            int p = tid + i * 256;
            int row = p >> 2, sl = p & 3, ssl = sl ^ ((row >> 1) & 3);
            gload16(B + (size_t)(col0 + row) * 1024 + k0 + ssl * 8, (char*)lB[buf] + p * 16);
        }
    };

    stage(0, 0);
    __syncthreads();
    int buf = 0;
    for (int k0 = 0; k0 < 1024; k0 += 32) {
        if (k0 + 32 < 1024) stage(buf ^ 1, k0 + 32);
        __builtin_amdgcn_s_setprio(1);
        bf16x8 af[4], bf[4];
        #pragma unroll
        for (int i = 0; i < 4; i++) {
            int r = wrow + i * 16 + frow;
            int sl = koct ^ ((r >> 1) & 3);
            af[i] = *(const bf16x8*)((const char*)lA[buf] + r * 64 + sl * 16);
        }
        #pragma unroll
        for (int j = 0; j < 4; j++) {
            int r = wcol + j * 16 + frow;
            int sl = koct ^ ((r >> 1) & 3);
            bf[j] = *(const bf16x8*)((const char*)lB[buf] + r * 64 + sl * 16);
        }
        if (sel < 2) {
            // swapped: D col-axis = token (af frow), q-axis = channel (bf rows)
            #pragma unroll
            for (int i = 0; i < 4; i++)
                #pragma unroll
                for (int j = 0; j < 4; j++)
                    acc[i][j] = __builtin_amdgcn_mfma_f32_16x16x32_bf16(bf[j], af[i], acc[i][j], 0, 0, 0);
        } else {
            #pragma unroll
            for (int i = 0; i < 4; i++)
                #pragma unroll
                for (int j = 0; j < 4; j++)
                    acc[i][j] = __builtin_amdgcn_mfma_f32_16x16x32_bf16(af[i], bf[j], acc[i][j], 0, 0, 0);
        }
        __builtin_amdgcn_s_setprio(0);
        __syncthreads();
        buf ^= 1;
    }

    if (sel < 2) {
        const float scale = (sel == 0) ? 0.125f * LOG2E : 1.0f;
        u16* outp = (sel == 0) ? Qh : Kh;
        #pragma unroll
        for (int i = 0; i < 4; i++) {
            int tok = row0 + wrow + i * 16 + frow;
            #pragma unroll
            for (int j = 0; j < 4; j++) {
                int c0 = col0 + wcol + j * 16 + koct * 4;   // channel base (mult of 4)
                int zz = (c0 >> 6) * 4 + (tok >> 10);
                uint2 pk;
                pk.x = cvt_pk_bf16(acc[i][j][0] * scale, acc[i][j][1] * scale);
                pk.y = cvt_pk_bf16(acc[i][j][2] * scale, acc[i][j][3] * scale);
                *(uint2*)(outp + (size_t)zz * 65536 +
                          (size_t)(tok & 1023) * 64 + (c0 & 63)) = pk;
            }
        }
    } else {
        #pragma unroll
        for (int i = 0; i < 4; i++) {
            int r0 = row0 + wrow + i * 16 + koct * 4;   // token base (mult of 4)
            #pragma unroll
            for (int j = 0; j < 4; j++) {
                int c = col0 + wcol + j * 16 + frow;    // channel
                int z = (c >> 6) * 4 + (r0 >> 10);
                uint2 pk;
                pk.x = cvt_pk_bf16(acc[i][j][0], acc[i][j][1]);
                pk.y = cvt_pk_bf16(acc[i][j][2], acc[i][j][3]);
                *(uint2*)(Vt + (size_t)z * 65536 + (size_t)(c & 63) * 1024 + (r0 & 1023)) = pk;
            }
        }
    }
}

// ---------------------------------------------------------------------------
// bf16 MFMA GEMM for FFN, 2-buf. MODE 2: +bias+relu bf16. MODE 3: +bias bf16.
// ---------------------------------------------------------------------------
template <int MODE>
__launch_bounds__(256)
__global__ void gemm_bt(const u16* __restrict__ A, const u16* __restrict__ B,
                        const float* __restrict__ bias, u16* __restrict__ outp)
{
    __shared__ __align__(16) u16 lA[2][128 * 64];
    __shared__ __align__(16) u16 lB[2][64 * 64];
    const int tid = threadIdx.x, lane = tid & 63, w = tid >> 6;
    const int frow = lane & 15, koct = lane >> 4;
    const int col0 = blockIdx.x * 64, row0 = blockIdx.y * 128;
    const int wrow = (w >> 1) * 64, wcol = (w & 1) * 32;
    f32x4 acc[4][2] = {};

    auto stage = [&](int buf, int k0) {
        #pragma unroll
        for (int i = 0; i < 4; i++) {
            int p = tid + i * 256;
            int row = p >> 3, sl = p & 7, ssl = sl ^ (row & 7);
            gload16(A + (size_t)(row0 + row) * 1024 + k0 + ssl * 8, (char*)lA[buf] + p * 16);
        }
        #pragma unroll
        for (int i = 0; i < 2; i++) {
            int p = tid + i * 256;
            int row = p >> 3, sl = p & 7, ssl = sl ^ (row & 7);
            gload16(B + (size_t)(col0 + row) * 1024 + k0 + ssl * 8, (char*)lB[buf] + p * 16);
        }
    };

    stage(0, 0);
    __syncthreads();
    int buf = 0;
    for (int k0 = 0; k0 < 1024; k0 += 64) {
        if (k0 + 64 < 1024) stage(buf ^ 1, k0 + 64);
        __builtin_amdgcn_s_setprio(1);
        #pragma unroll
        for (int ks = 0; ks < 2; ks++) {
            bf16x8 af[4], bf2[2];
            #pragma unroll
            for (int i = 0; i < 4; i++) {
                int r = wrow + i * 16 + frow;
                int sl = (ks * 4 + koct) ^ (r & 7);
                af[i] = *(const bf16x8*)((const char*)lA[buf] + r * 128 + sl * 16);
            }
            #pragma unroll
            for (int j = 0; j < 2; j++) {
                int r = wcol + j * 16 + frow;
                int sl = (ks * 4 + koct) ^ (r & 7);
                bf2[j] = *(const bf16x8*)((const char*)lB[buf] + r * 128 + sl * 16);
            }
            #pragma unroll
            for (int i = 0; i < 4; i++)
                #pragma unroll
                for (int j = 0; j < 2; j++)
                    acc[i][j] = __builtin_amdgcn_mfma_f32_16x16x32_bf16(af[i], bf2[j], acc[i][j], 0, 0, 0);
        }
        __builtin_amdgcn_s_setprio(0);
        __syncthreads();
        buf ^= 1;
    }

    #pragma unroll
    for (int i = 0; i < 4; i++)
        #pragma unroll
        for (int j = 0; j < 2; j++)
            #pragma unroll
            for (int q = 0; q < 4; q++) {
                int r = row0 + wrow + i * 16 + koct * 4 + q;
                int c = col0 + wcol + j * 16 + frow;
                float v = acc[i][j][q] + bias[c];
                if constexpr (MODE == 2) v = fmaxf(v, 0.f);
                outp[(size_t)r * 1024 + c] = f2bf(v);
            }
}

// ---------------------------------------------------------------------------
// Pass 1: partial[zg][n][m] = sum_{z in zg*16..+16} exp2(s'_znm) * km01(z,m)
// 1-D grid 1024, XCD-swizzled: XCD c owns one zg x 8 m-tiles.
// ---------------------------------------------------------------------------
__launch_bounds__(256)
__global__ void attn_pass1(const u16* __restrict__ Qh, const u16* __restrict__ Kh,
                           const float* __restrict__ km, float* __restrict__ partial)
{
    const int bid = blockIdx.x;
    const int mtzg = (bid & 7) * 8 + ((bid >> 3) & 7);   // cluster per XCD
    const int m0 = (mtzg & 15) * 64, zg = mtzg >> 4;
    const int n0 = (bid >> 6) * 64;

    __shared__ __align__(16) u16 lQ[2][64 * 64];
    __shared__ __align__(16) u16 lK[2][64 * 64];
    const int tid = threadIdx.x, lane = tid & 63, w = tid >> 6;
    const int frow = lane & 15, koct = lane >> 4;
    const int wn = (w >> 1) * 32, wm = (w & 1) * 32;
    f32x4 ssum[2][2] = {};

    auto stage = [&](int buf, int z) {
        #pragma unroll
        for (int i = 0; i < 2; i++) {
            int p = tid + i * 256;
            int row = p >> 3, sl = p & 7, ssl = sl ^ (row & 7);
            gload16(Qh + (size_t)(z * NSEQ + n0 + row) * 64 + ssl * 8, (char*)lQ[buf] + p * 16);
            gload16(Kh + (size_t)(z * NSEQ + m0 + row) * 64 + ssl * 8, (char*)lK[buf] + p * 16);
        }
    };

    const int z0 = zg * 16;
    stage(0, z0);
    __syncthreads();
    int buf = 0;
    for (int zi = 0; zi < 16; zi++) {
        const int z = z0 + zi;
        if (zi < 15) stage(buf ^ 1, z + 1);
        f32x4 km4[2];
        #pragma unroll
        for (int j = 0; j < 2; j++)
            km4[j] = *(const f32x4*)(km + z * NSEQ + m0 + wm + j * 16 + koct * 4);
        f32x4 s[2][2] = {};
        __builtin_amdgcn_s_setprio(1);
        #pragma unroll
        for (int ks = 0; ks < 2; ks++) {
            bf16x8 a[2], b2[2];
            #pragma unroll
            for (int i = 0; i < 2; i++) {
                int r = wn + i * 16 + frow;
                int sl = (ks * 4 + koct) ^ (r & 7);
                a[i] = *(const bf16x8*)((const char*)lQ[buf] + r * 128 + sl * 16);
            }
            #pragma unroll
            for (int j = 0; j < 2; j++) {
                int r = wm + j * 16 + frow;
                int sl = (ks * 4 + koct) ^ (r & 7);
                b2[j] = *(const bf16x8*)((const char*)lK[buf] + r * 128 + sl * 16);
            }
            #pragma unroll
            for (int i = 0; i < 2; i++)
                #pragma unroll
                for (int j = 0; j < 2; j++)
                    s[i][j] = __builtin_amdgcn_mfma_f32_16x16x32_bf16(b2[j], a[i], s[i][j], 0, 0, 0);
        }
        __builtin_amdgcn_s_setprio(0);
        #pragma unroll
        for (int j = 0; j < 2; j++)
            #pragma unroll
            for (int i = 0; i < 2; i++)
                #pragma unroll
                for (int q = 0; q < 4; q++)
                    ssum[i][j][q] += __builtin_amdgcn_exp2f(s[i][j][q]) * km4[j][q];
        __syncthreads();
        buf ^= 1;
    }
    #pragma unroll
    for (int i = 0; i < 2; i++)
        #pragma unroll
        for (int j = 0; j < 2; j++) {
            int ng = n0 + wn + i * 16 + frow;
            int mg = m0 + wm + j * 16 + koct * 4;
            *(f32x4*)(partial + (size_t)zg * 1048576 + (size_t)ng * NSEQ + mg) = ssum[i][j];
        }
}

// invS = 1 / (p0+p1+p2+p3)
__launch_bounds__(256)
__global__ void sum_inv(const float* __restrict__ p, float* __restrict__ invS) {
    int i = (blockIdx.x * 256 + threadIdx.x) * 4;
    float4 a = *(const float4*)(p + i);
    float4 b = *(const float4*)(p + 1048576 + i);
    float4 c = *(const float4*)(p + 2097152 + i);
    float4 d = *(const float4*)(p + 3145728 + i);
    float4 r;
    float s;
    s = a.x + b.x + c.x + d.x; r.x = s > 0.f ? 1.f / s : 0.f;
    s = a.y + b.y + c.y + d.y; r.y = s > 0.f ? 1.f / s : 0.f;
    s = a.z + b.z + c.z + d.z; r.z = s > 0.f ? 1.f / s : 0.f;
    s = a.w + b.w + c.w + d.w; r.w = s > 0.f ? 1.f / s : 0.f;
    *(float4*)(invS + i) = r;
}

// ---------------------------------------------------------------------------
// Pass 2 (R7 structure, bf16 output): per z, out = sum_m (exp2(s')*invS) V'[m,:]
// m-tile 64, double-buffered staging, wave-private lP, 1 barrier per tile.
// grid 1024, XCD c owns z in {8c..8c+7}.
// ---------------------------------------------------------------------------
__launch_bounds__(256)
__global__ void attn_pass2(const u16* __restrict__ Qh, const u16* __restrict__ Kh,
                           const u16* __restrict__ Vt,
                           const float* __restrict__ qm, const float* __restrict__ invS,
                           const u8* __restrict__ pad, u16* __restrict__ attn)
{
    const int bid = blockIdx.x;
    const int z  = (bid & 7) * 8 + ((bid >> 3) & 7);     // cluster per XCD
    const int n0 = (bid >> 6) * 64;

    __shared__ __align__(16) u16 lK[2][64 * 64];
    __shared__ __align__(16) u16 lV[2][64 * 64];   // Vt tile: [d][m]
    __shared__ __align__(16) u16 lP[64 * 64];
    const int tid = threadIdx.x, lane = tid & 63, w = tid >> 6;
    const int frow = lane & 15, koct = lane >> 4;
    const int hh = z >> 2, bb = z & 3;
    const int wrow = w * 16;
    const int nl_row = wrow + frow;
    const size_t inv_base = (size_t)(n0 + nl_row) * NSEQ;

    bf16x8 aq[2];
    #pragma unroll
    for (int ks = 0; ks < 2; ks++)
        aq[ks] = *(const bf16x8*)(Qh + (size_t)(z * NSEQ + n0 + nl_row) * 64 + ks * 32 + koct * 8);

    auto stage = [&](int buf, int m0) {
        #pragma unroll
        for (int i = 0; i < 2; i++) {
            int p = tid + i * 256;
            int row = p >> 3, sl = p & 7, ssl = sl ^ (row & 7);
            gload16(Kh + (size_t)(z * NSEQ + m0 + row) * 64 + ssl * 8, (char*)lK[buf] + p * 16);
            gload16(Vt + (size_t)z * 65536 + (size_t)row * 1024 + m0 + ssl * 8, (char*)lV[buf] + p * 16);
        }
    };

    f32x4 oacc[4] = {};
    f32x4 iv[4];
    #pragma unroll
    for (int j = 0; j < 4; j++)
        iv[j] = *(const f32x4*)(invS + inv_base + j * 16 + koct * 4);
    stage(0, 0);
    __syncthreads();
    int buf = 0;

    for (int mt = 0; mt < 16; mt++) {
        const int m0 = mt * 64;
        if (mt < 15) stage(buf ^ 1, m0 + 64);
        f32x4 ivn[4];
        if (mt < 15) {
            #pragma unroll
            for (int j = 0; j < 4; j++)
                ivn[j] = *(const f32x4*)(invS + inv_base + m0 + 64 + j * 16 + koct * 4);
        }
        f32x4 s[4] = {};
        __builtin_amdgcn_s_setprio(1);
        #pragma unroll
        for (int ks = 0; ks < 2; ks++) {
            bf16x8 kb[4];
            #pragma unroll
            for (int j = 0; j < 4; j++) {
                int r = j * 16 + frow;
                int sl = (ks * 4 + koct) ^ (r & 7);
                kb[j] = *(const bf16x8*)((const char*)lK[buf] + r * 128 + sl * 16);
            }
            #pragma unroll
            for (int j = 0; j < 4; j++)
                s[j] = __builtin_amdgcn_mfma_f32_16x16x32_bf16(kb[j], aq[ks], s[j], 0, 0, 0);
        }
        __builtin_amdgcn_s_setprio(0);
        #pragma unroll
        for (int j = 0; j < 4; j++) {
            float p0 = __builtin_amdgcn_exp2f(s[j][0]) * iv[j][0];
            float p1 = __builtin_amdgcn_exp2f(s[j][1]) * iv[j][1];
            float p2 = __builtin_amdgcn_exp2f(s[j][2]) * iv[j][2];
            float p3 = __builtin_amdgcn_exp2f(s[j][3]) * iv[j][3];
            uint2 pk;
            pk.x = cvt_pk_bf16(p0, p1);
            pk.y = cvt_pk_bf16(p2, p3);
            int slot = (j * 2 + (koct >> 1)) ^ (nl_row & 7);
            *(uint2*)((char*)lP + nl_row * 128 + slot * 16 + (koct & 1) * 8) = pk;
        }
        __builtin_amdgcn_s_setprio(1);
        #pragma unroll
        for (int ks = 0; ks < 2; ks++) {
            int sl = (ks * 4 + koct) ^ (nl_row & 7);
            bf16x8 pa = *(const bf16x8*)((const char*)lP + nl_row * 128 + sl * 16);
            bf16x8 vb[4];
            #pragma unroll
            for (int dj = 0; dj < 4; dj++) {
                int rr = dj * 16 + frow;
                int sv = (ks * 4 + koct) ^ (rr & 7);
                vb[dj] = *(const bf16x8*)((const char*)lV[buf] + rr * 128 + sv * 16);
            }
            #pragma unroll
            for (int dj = 0; dj < 4; dj++)
                oacc[dj] = __builtin_amdgcn_mfma_f32_16x16x32_bf16(pa, vb[dj], oacc[dj], 0, 0, 0);
        }
        __builtin_amdgcn_s_setprio(0);
        __syncthreads();
        buf ^= 1;
        #pragma unroll
        for (int j = 0; j < 4; j++) iv[j] = ivn[j];
    }

    #pragma unroll
    for (int q = 0; q < 4; q++) {
        int ns = n0 + wrow + koct * 4 + q;
        float f = qm[z * NSEQ + ns] * (pad[bb * NSEQ + ns] ? 0.f : 1.f);
        #pragma unroll
        for (int dj = 0; dj < 4; dj++) {
            int d = dj * 16 + frow;
            attn[(size_t)(bb * NSEQ + ns) * DMODEL + hh * 64 + d] = f2bf(oacc[dj][q] * f);
        }
    }
}

// ---------------------------------------------------------------------------
// LayerNorm over last dim (1024), one block per row.
// MODE 0: A bf16 + B bf16 -> v = a+b ; out bf16 (hb) only.
// MODE 1: A bf16, B bf16 -> v = a*valid + b ; out f32 * valid (final).
// ---------------------------------------------------------------------------
template <int MODE>
__launch_bounds__(256)
__global__ void ln_kernel(const u16* __restrict__ Ap, const u16* __restrict__ Bp,
                          const float* __restrict__ g, const float* __restrict__ beta,
                          const u8* __restrict__ pad,
                          float* __restrict__ outf, u16* __restrict__ outb)
{
    const int row = blockIdx.x, tid = threadIdx.x;
    const int lane = tid & 63, wv = tid >> 6;
    const float valid = pad[row] ? 0.f : 1.f;
    __shared__ float red[4];

    uint2 aav = *(const uint2*)(Ap + (size_t)row * 1024 + tid * 4);
    uint2 bbv = *(const uint2*)(Bp + (size_t)row * 1024 + tid * 4);
    float v[4];
    if constexpr (MODE == 0) {
        v[0] = bf2f(aav.x & 0xFFFFu) + bf2f(bbv.x & 0xFFFFu);
        v[1] = bf2f(aav.x >> 16)     + bf2f(bbv.x >> 16);
        v[2] = bf2f(aav.y & 0xFFFFu) + bf2f(bbv.y & 0xFFFFu);
        v[3] = bf2f(aav.y >> 16)     + bf2f(bbv.y >> 16);
    } else {
        v[0] = bf2f(aav.x & 0xFFFFu) * valid + bf2f(bbv.x & 0xFFFFu);
        v[1] = bf2f(aav.x >> 16)     * valid + bf2f(bbv.x >> 16);
        v[2] = bf2f(aav.y & 0xFFFFu) * valid + bf2f(bbv.y & 0xFFFFu);
        v[3] = bf2f(aav.y >> 16)     * valid + bf2f(bbv.y >> 16);
    }
    float s = v[0] + v[1] + v[2] + v[3];
    #pragma unroll
    for (int off = 32; off > 0; off >>= 1) s += __shfl_down(s, off, 64);
    if (lane == 0) red[wv] = s;
    __syncthreads();
    float mean = (red[0] + red[1] + red[2] + red[3]) * (1.f / 1024.f);
    float sq = 0.f;
    #pragma unroll
    for (int k = 0; k < 4; k++) { float d = v[k] - mean; sq += d * d; }
    __syncthreads();
    #pragma unroll
    for (int off = 32; off > 0; off >>= 1) sq += __shfl_down(sq, off, 64);
    if (lane == 0) red[wv] = sq;
    __syncthreads();
    float var = (red[0] + red[1] + red[2] + red[3]) * (1.f / 1024.f);
    float rstd = rsqrtf(var + 1e-5f);

    if constexpr (MODE == 0) {
        uint2 o;
        float o0 = (v[0] - mean) * rstd * g[tid * 4 + 0] + beta[tid * 4 + 0];
        float o1 = (v[1] - mean) * rstd * g[tid * 4 + 1] + beta[tid * 4 + 1];
        float o2 = (v[2] - mean) * rstd * g[tid * 4 + 2] + beta[tid * 4 + 2];
        float o3 = (v[3] - mean) * rstd * g[tid * 4 + 3] + beta[tid * 4 + 3];
        o.x = cvt_pk_bf16(o0, o1);
        o.y = cvt_pk_bf16(o2, o3);
        *(uint2*)(outb + (size_t)row * 1024 + tid * 4) = o;
    } else {
        float4 o;
        o.x = ((v[0] - mean) * rstd * g[tid * 4 + 0] + beta[tid * 4 + 0]) * valid;
        o.y = ((v[1] - mean) * rstd * g[tid * 4 + 1] + beta[tid * 4 + 1]) * valid;
        o.z = ((v[2] - mean) * rstd * g[tid * 4 + 2] + beta[tid * 4 + 2]) * valid;
        o.w = ((v[3] - mean) * rstd * g[tid * 4 + 3] + beta[tid * 4 + 3]) * valid;
        *(float4*)(outf + (size_t)row * 1024 + tid * 4) = o;
    }
}

// ---------------------------------------------------------------------------
extern "C" void kernel_launch(void* const* d_in, const int* in_sizes, int n_in,
                              void* d_out, int out_size, void* d_ws, size_t ws_size,
                              hipStream_t stream)
{
    const float* x   = (const float*)d_in[0];
    const u8*    pad = (const u8*)d_in[1];
    const float* Wq  = (const float*)d_in[2];
    const float* Wk  = (const float*)d_in[3];
    const float* Wv  = (const float*)d_in[4];
    const float* W1  = (const float*)d_in[5];
    const float* b1  = (const float*)d_in[6];
    const float* W2  = (const float*)d_in[7];
    const float* b2  = (const float*)d_in[8];
    const float* g1  = (const float*)d_in[9];
    const float* be1 = (const float*)d_in[10];
    const float* g2  = (const float*)d_in[11];
    const float* be2 = (const float*)d_in[12];
    float* out = (float*)d_out;

    // workspace (~95 MB)
    u16* xb    = (u16*)d_ws;
    u16* Wqb   = xb    + 4194304;
    u16* Wkb   = Wqb   + 1048576;
    u16* Wvb   = Wkb   + 1048576;
    u16* W1b   = Wvb   + 1048576;
    u16* W2b   = W1b   + 1048576;
    u16* Qh    = W2b   + 1048576;        // [z][n][dh]
    u16* Kh    = Qh    + 4194304;        // [z][n][dh]
    u16* Vt    = Kh    + 4194304;        // [z][dh][n]  (km applied by vt_km)
    u16* hb    = Vt    + 4194304;        // LN1 output, bf16
    u16* ff1b  = hb    + 4194304;
    u16* ffb   = ff1b  + 4194304;        // FFN2 output, bf16
    u16* attnb = ffb   + 4194304;        // attention output, bf16
    float* km      = (float*)(attnb + 4194304);
    float* qm      = km      + 65536;
    float* partial = qm      + 65536;           // 4M f32
    float* invS    = partial + 4194304;         // 1M f32

    P5 p5;
    p5.in[0] = Wq; p5.in[1] = Wk; p5.in[2] = Wv; p5.in[3] = W1; p5.in[4] = W2;
    p5.out[0] = Wqb; p5.out[1] = Wkb; p5.out[2] = Wvb; p5.out[3] = W1b; p5.out[4] = W2b;
    cvt_all<<<9216, 256, 0, stream>>>(x, xb, p5);

    // fused Q/K/V projections, m97-structure 128x128 tiles (2-buf)
    gemm_qkv<<<dim3(24, 32), 256, 0, stream>>>(xb, Wqb, Wkb, Wvb, Qh, Kh, Vt);

    rowmask2_bf<<<512, 256, 0, stream>>>(Kh, Qh, km, qm);
    vt_km<<<4096, 256, 0, stream>>>(Vt, km);

    attn_pass1<<<1024, 256, 0, stream>>>(Qh, Kh, km, partial);
    sum_inv<<<1024, 256, 0, stream>>>(partial, invS);
    attn_pass2<<<1024, 256, 0, stream>>>(Qh, Kh, Vt, qm, invS, pad, attnb);

    // h = LN(xb + attn) -> bf16 only
    ln_kernel<0><<<4096, 256, 0, stream>>>(xb, attnb, g1, be1, pad, nullptr, hb);

    // FFN (both outputs bf16)
    gemm_bt<2><<<dim3(16, 32), 256, 0, stream>>>(hb,   W1b, b1, ff1b);
    gemm_bt<3><<<dim3(16, 32), 256, 0, stream>>>(ff1b, W2b, b2, ffb);

    // out = LN(ff*valid + h) * valid  (final f32)
    ln_kernel<1><<<4096, 256, 0, stream>>>(ffb, hb, g2, be2, pad, out, nullptr);
}

// Round 15
// 192.899 us; speedup vs baseline: 1.0235x; 1.0235x over previous
//
#include <hip/hip_runtime.h>
#include <math.h>

typedef unsigned short u16;
typedef unsigned char  u8;
typedef unsigned int   u32;
typedef __attribute__((ext_vector_type(8))) short bf16x8;
typedef __attribute__((ext_vector_type(4))) float f32x4;

#define NSEQ   1024
#define DMODEL 1024
#define ZTOT   64
#define LOG2E  1.4426950408889634f

typedef const __attribute__((address_space(1))) void* gp1;
typedef __attribute__((address_space(3))) void* lp3;

__device__ __forceinline__ void gload16(const void* g, void* l) {
    __builtin_amdgcn_global_load_lds((gp1)g, (lp3)l, 16, 0, 0);
}

__device__ __forceinline__ u16 f2bf(float f) {
    u32 u = __builtin_bit_cast(u32, f);
    return (u16)((u + 0x7FFFu + ((u >> 16) & 1u)) >> 16);
}

__device__ __forceinline__ float bf2f(u32 lo16) {
    u32 t = lo16 << 16;
    return __builtin_bit_cast(float, t);
}

// HW packed f32->bf16 (RNE), 2 values -> 1 dword
__device__ __forceinline__ u32 cvt_pk_bf16(float a, float b) {
    u32 r;
    asm("v_cvt_pk_bf16_f32 %0, %1, %2" : "=v"(r) : "v"(a), "v"(b));
    return r;
}

// ---------------------------------------------------------------------------
// fp32 -> bf16 elementwise: x (4M elems) + 5 weights (1M each) in ONE launch.
// ---------------------------------------------------------------------------
struct P5 { const float* in[5]; u16* out[5]; };
__launch_bounds__(256)
__global__ void cvt_all(const float* __restrict__ x, u16* __restrict__ xb, P5 p) {
    int bid = blockIdx.x;
    const float* in;
    u16* out;
    int blk;
    if (bid < 4096) { in = x; out = xb; blk = bid; }
    else {
        int which = (bid - 4096) >> 10;
        blk = bid & 1023;
        in = p.in[which];
        out = p.out[which];
    }
    int i = (blk * 256 + threadIdx.x) * 4;
    float4 v = *(const float4*)(in + i);
    uint2 o;
    o.x = cvt_pk_bf16(v.x, v.y);
    o.y = cvt_pk_bf16(v.z, v.w);
    *(uint2*)(out + i) = o;
}

// sign(sum |row|) over 64 bf16 -> 0/1 ; grid 512: first half Kh->km, second Qh->qm
__launch_bounds__(256)
__global__ void rowmask2_bf(const u16* __restrict__ Kh, const u16* __restrict__ Qh,
                            float* __restrict__ km, float* __restrict__ qm) {
    int b = blockIdx.x;
    const u16* T = (b < 256) ? Kh : Qh;
    float* o = (b < 256) ? km : qm;
    int r = (b & 255) * 256 + threadIdx.x;
    const uint4* p = (const uint4*)(T + (size_t)r * 64);
    u32 acc = 0;
    #pragma unroll
    for (int i = 0; i < 8; i++) {
        uint4 q = p[i];
        acc |= (q.x | q.y | q.z | q.w) & 0x7fff7fffu;
    }
    o[r] = acc ? 1.f : 0.f;
}

// Vt[z][dh][tok] &= (km[z][tok] != 0)
__launch_bounds__(256)
__global__ void vt_km(u16* __restrict__ Vt, const float* __restrict__ km) {
    int idx = blockIdx.x * 256 + threadIdx.x;  // uint4 index (8 bf16)
    int e0 = idx * 8;
    int z = e0 >> 16;
    int tok = e0 & 1023;
    float4 ka = *(const float4*)(km + z * 1024 + tok);
    float4 kb = *(const float4*)(km + z * 1024 + tok + 4);
    uint4 v = *(uint4*)(Vt + e0);
    u32 m;
    m = (ka.x != 0.f ? 0x0000FFFFu : 0u) | (ka.y != 0.f ? 0xFFFF0000u : 0u); v.x &= m;
    m = (ka.z != 0.f ? 0x0000FFFFu : 0u) | (ka.w != 0.f ? 0xFFFF0000u : 0u); v.y &= m;
    m = (kb.x != 0.f ? 0x0000FFFFu : 0u) | (kb.y != 0.f ? 0xFFFF0000u : 0u); v.z &= m;
    m = (kb.z != 0.f ? 0x0000FFFFu : 0u) | (kb.w != 0.f ? 0xFFFF0000u : 0u); v.w &= m;
    *(uint4*)(Vt + e0) = v;
}

// ---------------------------------------------------------------------------
// Q/K projection GEMM (swapped operands): BM=BN=128, BK=32, 4 waves, 2-buf.
// grid (16, 32): sel = bx>>3 picks {Q, K}; col0 = (bx&7)*128.
// Swapped MFMA puts channel on q-axis -> 8B packed head-major stores.
// ---------------------------------------------------------------------------
__launch_bounds__(256)
__global__ void gemm_qk(const u16* __restrict__ A,
                        const u16* __restrict__ Wq, const u16* __restrict__ Wk,
                        u16* __restrict__ Qh, u16* __restrict__ Kh)
{
    __shared__ __align__(16) u16 lA[2][128 * 32];
    __shared__ __align__(16) u16 lB[2][128 * 32];
    const int tid = threadIdx.x, lane = tid & 63, w = tid >> 6;
    const int frow = lane & 15, koct = lane >> 4;
    const int sel = blockIdx.x >> 3;
    const int col0 = (blockIdx.x & 7) * 128, row0 = blockIdx.y * 128;
    const u16* B = sel ? Wk : Wq;
    const int wrow = (w >> 1) * 64, wcol = (w & 1) * 64;
    f32x4 acc[4][4] = {};

    auto stage = [&](int buf, int k0) {
        #pragma unroll
        for (int i = 0; i < 2; i++) {
            int p = tid + i * 256;
            int row = p >> 2, sl = p & 3, ssl = sl ^ ((row >> 1) & 3);
            gload16(A + (size_t)(row0 + row) * 1024 + k0 + ssl * 8, (char*)lA[buf] + p * 16);
        }
        #pragma unroll
        for (int i = 0; i < 2; i++) {
            int p = tid + i * 256;
            int row = p >> 2, sl = p & 3, ssl = sl ^ ((row >> 1) & 3);
            gload16(B + (size_t)(col0 + row) * 1024 + k0 + ssl * 8, (char*)lB[buf] + p * 16);
        }
    };

    stage(0, 0);
    __syncthreads();
    int buf = 0;
    for (int k0 = 0; k0 < 1024; k0 += 32) {
        if (k0 + 32 < 1024) stage(buf ^ 1, k0 + 32);
        __builtin_amdgcn_s_setprio(1);
        bf16x8 af[4], bf[4];
        #pragma unroll
        for (int i = 0; i < 4; i++) {
            int r = wrow + i * 16 + frow;
            int sl = koct ^ ((r >> 1) & 3);
            af[i] = *(const bf16x8*)((const char*)lA[buf] + r * 64 + sl * 16);
        }
        #pragma unroll
        for (int j = 0; j < 4; j++) {
            int r = wcol + j * 16 + frow;
            int sl = koct ^ ((r >> 1) & 3);
            bf[j] = *(const bf16x8*)((const char*)lB[buf] + r * 64 + sl * 16);
        }
        // swapped: D col-axis = token (af frow), q-axis = channel (bf rows)
        #pragma unroll
        for (int i = 0; i < 4; i++)
            #pragma unroll
            for (int j = 0; j < 4; j++)
                acc[i][j] = __builtin_amdgcn_mfma_f32_16x16x32_bf16(bf[j], af[i], acc[i][j], 0, 0, 0);
        __builtin_amdgcn_s_setprio(0);
        __syncthreads();
        buf ^= 1;
    }

    const float scale = sel ? 1.0f : 0.125f * LOG2E;
    u16* outp = sel ? Kh : Qh;
    #pragma unroll
    for (int i = 0; i < 4; i++) {
        int tok = row0 + wrow + i * 16 + frow;
        #pragma unroll
        for (int j = 0; j < 4; j++) {
            int c0 = col0 + wcol + j * 16 + koct * 4;   // channel base (mult of 4)
            int zz = (c0 >> 6) * 4 + (tok >> 10);
            uint2 pk;
            pk.x = cvt_pk_bf16(acc[i][j][0] * scale, acc[i][j][1] * scale);
            pk.y = cvt_pk_bf16(acc[i][j][2] * scale, acc[i][j][3] * scale);
            *(uint2*)(outp + (size_t)zz * 65536 +
                      (size_t)(tok & 1023) * 64 + (c0 & 63)) = pk;
        }
    }
}

// ---------------------------------------------------------------------------
// V projection GEMM (unswapped): grid (8, 32); Vt [z][dh][tok] 8B stores.
// ---------------------------------------------------------------------------
__launch_bounds__(256)
__global__ void gemm_v(const u16* __restrict__ A, const u16* __restrict__ Wv,
                       u16* __restrict__ Vt)
{
    __shared__ __align__(16) u16 lA[2][128 * 32];
    __shared__ __align__(16) u16 lB[2][128 * 32];
    const int tid = threadIdx.x, lane = tid & 63, w = tid >> 6;
    const int frow = lane & 15, koct = lane >> 4;
    const int col0 = blockIdx.x * 128, row0 = blockIdx.y * 128;
    const int wrow = (w >> 1) * 64, wcol = (w & 1) * 64;
    f32x4 acc[4][4] = {};

    auto stage = [&](int buf, int k0) {
        #pragma unroll
        for (int i = 0; i < 2; i++) {
            int p = tid + i * 256;
            int row = p >> 2, sl = p & 3, ssl = sl ^ ((row >> 1) & 3);
            gload16(A + (size_t)(row0 + row) * 1024 + k0 + ssl * 8, (char*)lA[buf] + p * 16);
        }
        #pragma unroll
        for (int i = 0; i < 2; i++) {
            int p = tid + i * 256;
            int row = p >> 2, sl = p & 3, ssl = sl ^ ((row >> 1) & 3);
            gload16(Wv + (size_t)(col0 + row) * 1024 + k0 + ssl * 8, (char*)lB[buf] + p * 16);
        }
    };

    stage(0, 0);
    __syncthreads();
    int buf = 0;
    for (int k0 = 0; k0 < 1024; k0 += 32) {
        if (k0 + 32 < 1024) stage(buf ^ 1, k0 + 32);
        __builtin_amdgcn_s_setprio(1);
        bf16x8 af[4], bf[4];
        #pragma unroll
        for (int i = 0; i < 4; i++) {
            int r = wrow + i * 16 + frow;
            int sl = koct ^ ((r >> 1) & 3);
            af[i] = *(const bf16x8*)((const char*)lA[buf] + r * 64 + sl * 16);
        }
        #pragma unroll
        for (int j = 0; j < 4; j++) {
            int r = wcol + j * 16 + frow;
            int sl = koct ^ ((r >> 1) & 3);
            bf[j] = *(const bf16x8*)((const char*)lB[buf] + r * 64 + sl * 16);
        }
        #pragma unroll
        for (int i = 0; i < 4; i++)
            #pragma unroll
            for (int j = 0; j < 4; j++)
                acc[i][j] = __builtin_amdgcn_mfma_f32_16x16x32_bf16(af[i], bf[j], acc[i][j], 0, 0, 0);
        __builtin_amdgcn_s_setprio(0);
        __syncthreads();
        buf ^= 1;
    }

    #pragma unroll
    for (int i = 0; i < 4; i++) {
        int r0 = row0 + wrow + i * 16 + koct * 4;   // token base (mult of 4)
        #pragma unroll
        for (int j = 0; j < 4; j++) {
            int c = col0 + wcol + j * 16 + frow;    // channel
            int z = (c >> 6) * 4 + (r0 >> 10);
            uint2 pk;
            pk.x = cvt_pk_bf16(acc[i][j][0], acc[i][j][1]);
            pk.y = cvt_pk_bf16(acc[i][j][2], acc[i][j][3]);
            *(uint2*)(Vt + (size_t)z * 65536 + (size_t)(c & 63) * 1024 + (r0 & 1023)) = pk;
        }
    }
}

// ---------------------------------------------------------------------------
// bf16 MFMA GEMM for FFN, 2-buf. MODE 2: +bias+relu bf16. MODE 3: +bias bf16.
// ---------------------------------------------------------------------------
template <int MODE>
__launch_bounds__(256)
__global__ void gemm_bt(const u16* __restrict__ A, const u16* __restrict__ B,
                        const float* __restrict__ bias, u16* __restrict__ outp)
{
    __shared__ __align__(16) u16 lA[2][128 * 64];
    __shared__ __align__(16) u16 lB[2][64 * 64];
    const int tid = threadIdx.x, lane = tid & 63, w = tid >> 6;
    const int frow = lane & 15, koct = lane >> 4;
    const int col0 = blockIdx.x * 64, row0 = blockIdx.y * 128;
    const int wrow = (w >> 1) * 64, wcol = (w & 1) * 32;
    f32x4 acc[4][2] = {};

    auto stage = [&](int buf, int k0) {
        #pragma unroll
        for (int i = 0; i < 4; i++) {
            int p = tid + i * 256;
            int row = p >> 3, sl = p & 7, ssl = sl ^ (row & 7);
            gload16(A + (size_t)(row0 + row) * 1024 + k0 + ssl * 8, (char*)lA[buf] + p * 16);
        }
        #pragma unroll
        for (int i = 0; i < 2; i++) {
            int p = tid + i * 256;
            int row = p >> 3, sl = p & 7, ssl = sl ^ (row & 7);
            gload16(B + (size_t)(col0 + row) * 1024 + k0 + ssl * 8, (char*)lB[buf] + p * 16);
        }
    };

    stage(0, 0);
    __syncthreads();
    int buf = 0;
    for (int k0 = 0; k0 < 1024; k0 += 64) {
        if (k0 + 64 < 1024) stage(buf ^ 1, k0 + 64);
        __builtin_amdgcn_s_setprio(1);
        #pragma unroll
        for (int ks = 0; ks < 2; ks++) {
            bf16x8 af[4], bf2[2];
            #pragma unroll
            for (int i = 0; i < 4; i++) {
                int r = wrow + i * 16 + frow;
                int sl = (ks * 4 + koct) ^ (r & 7);
                af[i] = *(const bf16x8*)((const char*)lA[buf] + r * 128 + sl * 16);
            }
            #pragma unroll
            for (int j = 0; j < 2; j++) {
                int r = wcol + j * 16 + frow;
                int sl = (ks * 4 + koct) ^ (r & 7);
                bf2[j] = *(const bf16x8*)((const char*)lB[buf] + r * 128 + sl * 16);
            }
            #pragma unroll
            for (int i = 0; i < 4; i++)
                #pragma unroll
                for (int j = 0; j < 2; j++)
                    acc[i][j] = __builtin_amdgcn_mfma_f32_16x16x32_bf16(af[i], bf2[j], acc[i][j], 0, 0, 0);
        }
        __builtin_amdgcn_s_setprio(0);
        __syncthreads();
        buf ^= 1;
    }

    #pragma unroll
    for (int i = 0; i < 4; i++)
        #pragma unroll
        for (int j = 0; j < 2; j++)
            #pragma unroll
            for (int q = 0; q < 4; q++) {
                int r = row0 + wrow + i * 16 + koct * 4 + q;
                int c = col0 + wcol + j * 16 + frow;
                float v = acc[i][j][q] + bias[c];
                if constexpr (MODE == 2) v = fmaxf(v, 0.f);
                outp[(size_t)r * 1024 + c] = f2bf(v);
            }
}

// ---------------------------------------------------------------------------
// Pass 1: partial[zg][n][m] = sum_{z in zg*16..+16} exp2(s'_znm) * km01(z,m)
// 1-D grid 1024, XCD-swizzled: XCD c owns one zg x 8 m-tiles.
// ---------------------------------------------------------------------------
__launch_bounds__(256)
__global__ void attn_pass1(const u16* __restrict__ Qh, const u16* __restrict__ Kh,
                           const float* __restrict__ km, float* __restrict__ partial)
{
    const int bid = blockIdx.x;
    const int mtzg = (bid & 7) * 8 + ((bid >> 3) & 7);   // cluster per XCD
    const int m0 = (mtzg & 15) * 64, zg = mtzg >> 4;
    const int n0 = (bid >> 6) * 64;

    __shared__ __align__(16) u16 lQ[2][64 * 64];
    __shared__ __align__(16) u16 lK[2][64 * 64];
    const int tid = threadIdx.x, lane = tid & 63, w = tid >> 6;
    const int frow = lane & 15, koct = lane >> 4;
    const int wn = (w >> 1) * 32, wm = (w & 1) * 32;
    f32x4 ssum[2][2] = {};

    auto stage = [&](int buf, int z) {
        #pragma unroll
        for (int i = 0; i < 2; i++) {
            int p = tid + i * 256;
            int row = p >> 3, sl = p & 7, ssl = sl ^ (row & 7);
            gload16(Qh + (size_t)(z * NSEQ + n0 + row) * 64 + ssl * 8, (char*)lQ[buf] + p * 16);
            gload16(Kh + (size_t)(z * NSEQ + m0 + row) * 64 + ssl * 8, (char*)lK[buf] + p * 16);
        }
    };

    const int z0 = zg * 16;
    stage(0, z0);
    __syncthreads();
    int buf = 0;
    for (int zi = 0; zi < 16; zi++) {
        const int z = z0 + zi;
        if (zi < 15) stage(buf ^ 1, z + 1);
        f32x4 km4[2];
        #pragma unroll
        for (int j = 0; j < 2; j++)
            km4[j] = *(const f32x4*)(km + z * NSEQ + m0 + wm + j * 16 + koct * 4);
        f32x4 s[2][2] = {};
        __builtin_amdgcn_s_setprio(1);
        #pragma unroll
        for (int ks = 0; ks < 2; ks++) {
            bf16x8 a[2], b2[2];
            #pragma unroll
            for (int i = 0; i < 2; i++) {
                int r = wn + i * 16 + frow;
                int sl = (ks * 4 + koct) ^ (r & 7);
                a[i] = *(const bf16x8*)((const char*)lQ[buf] + r * 128 + sl * 16);
            }
            #pragma unroll
            for (int j = 0; j < 2; j++) {
                int r = wm + j * 16 + frow;
                int sl = (ks * 4 + koct) ^ (r & 7);
                b2[j] = *(const bf16x8*)((const char*)lK[buf] + r * 128 + sl * 16);
            }
            #pragma unroll
            for (int i = 0; i < 2; i++)
                #pragma unroll
                for (int j = 0; j < 2; j++)
                    s[i][j] = __builtin_amdgcn_mfma_f32_16x16x32_bf16(b2[j], a[i], s[i][j], 0, 0, 0);
        }
        __builtin_amdgcn_s_setprio(0);
        #pragma unroll
        for (int j = 0; j < 2; j++)
            #pragma unroll
            for (int i = 0; i < 2; i++)
                #pragma unroll
                for (int q = 0; q < 4; q++)
                    ssum[i][j][q] += __builtin_amdgcn_exp2f(s[i][j][q]) * km4[j][q];
        __syncthreads();
        buf ^= 1;
    }
    #pragma unroll
    for (int i = 0; i < 2; i++)
        #pragma unroll
        for (int j = 0; j < 2; j++) {
            int ng = n0 + wn + i * 16 + frow;
            int mg = m0 + wm + j * 16 + koct * 4;
            *(f32x4*)(partial + (size_t)zg * 1048576 + (size_t)ng * NSEQ + mg) = ssum[i][j];
        }
}

// invS = 1 / (p0+p1+p2+p3)
__launch_bounds__(256)
__global__ void sum_inv(const float* __restrict__ p, float* __restrict__ invS) {
    int i = (blockIdx.x * 256 + threadIdx.x) * 4;
    float4 a = *(const float4*)(p + i);
    float4 b = *(const float4*)(p + 1048576 + i);
    float4 c = *(const float4*)(p + 2097152 + i);
    float4 d = *(const float4*)(p + 3145728 + i);
    float4 r;
    float s;
    s = a.x + b.x + c.x + d.x; r.x = s > 0.f ? 1.f / s : 0.f;
    s = a.y + b.y + c.y + d.y; r.y = s > 0.f ? 1.f / s : 0.f;
    s = a.z + b.z + c.z + d.z; r.z = s > 0.f ? 1.f / s : 0.f;
    s = a.w + b.w + c.w + d.w; r.w = s > 0.f ? 1.f / s : 0.f;
    *(float4*)(invS + i) = r;
}

// ---------------------------------------------------------------------------
// Pass 2 (R7 structure, bf16 output): per z, out = sum_m (exp2(s')*invS) V'[m,:]
// m-tile 64, double-buffered staging, wave-private lP, 1 barrier per tile.
// grid 1024, XCD c owns z in {8c..8c+7}.
// ---------------------------------------------------------------------------
__launch_bounds__(256)
__global__ void attn_pass2(const u16* __restrict__ Qh, const u16* __restrict__ Kh,
                           const u16* __restrict__ Vt,
                           const float* __restrict__ qm, const float* __restrict__ invS,
                           const u8* __restrict__ pad, u16* __restrict__ attn)
{
    const int bid = blockIdx.x;
    const int z  = (bid & 7) * 8 + ((bid >> 3) & 7);     // cluster per XCD
    const int n0 = (bid >> 6) * 64;

    __shared__ __align__(16) u16 lK[2][64 * 64];
    __shared__ __align__(16) u16 lV[2][64 * 64];   // Vt tile: [d][m]
    __shared__ __align__(16) u16 lP[64 * 64];
    const int tid = threadIdx.x, lane = tid & 63, w = tid >> 6;
    const int frow = lane & 15, koct = lane >> 4;
    const int hh = z >> 2, bb = z & 3;
    const int wrow = w * 16;
    const int nl_row = wrow + frow;
    const size_t inv_base = (size_t)(n0 + nl_row) * NSEQ;

    bf16x8 aq[2];
    #pragma unroll
    for (int ks = 0; ks < 2; ks++)
        aq[ks] = *(const bf16x8*)(Qh + (size_t)(z * NSEQ + n0 + nl_row) * 64 + ks * 32 + koct * 8);

    auto stage = [&](int buf, int m0) {
        #pragma unroll
        for (int i = 0; i < 2; i++) {
            int p = tid + i * 256;
            int row = p >> 3, sl = p & 7, ssl = sl ^ (row & 7);
            gload16(Kh + (size_t)(z * NSEQ + m0 + row) * 64 + ssl * 8, (char*)lK[buf] + p * 16);
            gload16(Vt + (size_t)z * 65536 + (size_t)row * 1024 + m0 + ssl * 8, (char*)lV[buf] + p * 16);
        }
    };

    f32x4 oacc[4] = {};
    f32x4 iv[4];
    #pragma unroll
    for (int j = 0; j < 4; j++)
        iv[j] = *(const f32x4*)(invS + inv_base + j * 16 + koct * 4);
    stage(0, 0);
    __syncthreads();
    int buf = 0;

    for (int mt = 0; mt < 16; mt++) {
        const int m0 = mt * 64;
        if (mt < 15) stage(buf ^ 1, m0 + 64);
        f32x4 ivn[4];
        if (mt < 15) {
            #pragma unroll
            for (int j = 0; j < 4; j++)
                ivn[j] = *(const f32x4*)(invS + inv_base + m0 + 64 + j * 16 + koct * 4);
        }
        f32x4 s[4] = {};
        __builtin_amdgcn_s_setprio(1);
        #pragma unroll
        for (int ks = 0; ks < 2; ks++) {
            bf16x8 kb[4];
            #pragma unroll
            for (int j = 0; j < 4; j++) {
                int r = j * 16 + frow;
                int sl = (ks * 4 + koct) ^ (r & 7);
                kb[j] = *(const bf16x8*)((const char*)lK[buf] + r * 128 + sl * 16);
            }
            #pragma unroll
            for (int j = 0; j < 4; j++)
                s[j] = __builtin_amdgcn_mfma_f32_16x16x32_bf16(kb[j], aq[ks], s[j], 0, 0, 0);
        }
        __builtin_amdgcn_s_setprio(0);
        #pragma unroll
        for (int j = 0; j < 4; j++) {
            float p0 = __builtin_amdgcn_exp2f(s[j][0]) * iv[j][0];
            float p1 = __builtin_amdgcn_exp2f(s[j][1]) * iv[j][1];
            float p2 = __builtin_amdgcn_exp2f(s[j][2]) * iv[j][2];
            float p3 = __builtin_amdgcn_exp2f(s[j][3]) * iv[j][3];
            uint2 pk;
            pk.x = cvt_pk_bf16(p0, p1);
            pk.y = cvt_pk_bf16(p2, p3);
            int slot = (j * 2 + (koct >> 1)) ^ (nl_row & 7);
            *(uint2*)((char*)lP + nl_row * 128 + slot * 16 + (koct & 1) * 8) = pk;
        }
        __builtin_amdgcn_s_setprio(1);
        #pragma unroll
        for (int ks = 0; ks < 2; ks++) {
            int sl = (ks * 4 + koct) ^ (nl_row & 7);
            bf16x8 pa = *(const bf16x8*)((const char*)lP + nl_row * 128 + sl * 16);
            bf16x8 vb[4];
            #pragma unroll
            for (int dj = 0; dj < 4; dj++) {
                int rr = dj * 16 + frow;
                int sv = (ks * 4 + koct) ^ (rr & 7);
                vb[dj] = *(const bf16x8*)((const char*)lV[buf] + rr * 128 + sv * 16);
            }
            #pragma unroll
            for (int dj = 0; dj < 4; dj++)
                oacc[dj] = __builtin_amdgcn_mfma_f32_16x16x32_bf16(pa, vb[dj], oacc[dj], 0, 0, 0);
        }
        __builtin_amdgcn_s_setprio(0);
        __syncthreads();
        buf ^= 1;
        #pragma unroll
        for (int j = 0; j < 4; j++) iv[j] = ivn[j];
    }

    #pragma unroll
    for (int q = 0; q < 4; q++) {
        int ns = n0 + wrow + koct * 4 + q;
        float f = qm[z * NSEQ + ns] * (pad[bb * NSEQ + ns] ? 0.f : 1.f);
        #pragma unroll
        for (int dj = 0; dj < 4; dj++) {
            int d = dj * 16 + frow;
            attn[(size_t)(bb * NSEQ + ns) * DMODEL + hh * 64 + d] = f2bf(oacc[dj][q] * f);
        }
    }
}

// ---------------------------------------------------------------------------
// LayerNorm over last dim (1024), one block per row.
// MODE 0: A bf16 + B bf16 -> v = a+b ; out bf16 (hb) only.
// MODE 1: A bf16, B bf16 -> v = a*valid + b ; out f32 * valid (final).
// ---------------------------------------------------------------------------
template <int MODE>
__launch_bounds__(256)
__global__ void ln_kernel(const u16* __restrict__ Ap, const u16* __restrict__ Bp,
                          const float* __restrict__ g, const float* __restrict__ beta,
                          const u8* __restrict__ pad,
                          float* __restrict__ outf, u16* __restrict__ outb)
{
    const int row = blockIdx.x, tid = threadIdx.x;
    const int lane = tid & 63, wv = tid >> 6;
    const float valid = pad[row] ? 0.f : 1.f;
    __shared__ float red[4];

    uint2 aav = *(const uint2*)(Ap + (size_t)row * 1024 + tid * 4);
    uint2 bbv = *(const uint2*)(Bp + (size_t)row * 1024 + tid * 4);
    float v[4];
    if constexpr (MODE == 0) {
        v[0] = bf2f(aav.x & 0xFFFFu) + bf2f(bbv.x & 0xFFFFu);
        v[1] = bf2f(aav.x >> 16)     + bf2f(bbv.x >> 16);
        v[2] = bf2f(aav.y & 0xFFFFu) + bf2f(bbv.y & 0xFFFFu);
        v[3] = bf2f(aav.y >> 16)     + bf2f(bbv.y >> 16);
    } else {
        v[0] = bf2f(aav.x & 0xFFFFu) * valid + bf2f(bbv.x & 0xFFFFu);
        v[1] = bf2f(aav.x >> 16)     * valid + bf2f(bbv.x >> 16);
        v[2] = bf2f(aav.y & 0xFFFFu) * valid + bf2f(bbv.y & 0xFFFFu);
        v[3] = bf2f(aav.y >> 16)     * valid + bf2f(bbv.y >> 16);
    }
    float s = v[0] + v[1] + v[2] + v[3];
    #pragma unroll
    for (int off = 32; off > 0; off >>= 1) s += __shfl_down(s, off, 64);
    if (lane == 0) red[wv] = s;
    __syncthreads();
    float mean = (red[0] + red[1] + red[2] + red[3]) * (1.f / 1024.f);
    float sq = 0.f;
    #pragma unroll
    for (int k = 0; k < 4; k++) { float d = v[k] - mean; sq += d * d; }
    __syncthreads();
    #pragma unroll
    for (int off = 32; off > 0; off >>= 1) sq += __shfl_down(sq, off, 64);
    if (lane == 0) red[wv] = sq;
    __syncthreads();
    float var = (red[0] + red[1] + red[2] + red[3]) * (1.f / 1024.f);
    float rstd = rsqrtf(var + 1e-5f);

    if constexpr (MODE == 0) {
        uint2 o;
        float o0 = (v[0] - mean) * rstd * g[tid * 4 + 0] + beta[tid * 4 + 0];
        float o1 = (v[1] - mean) * rstd * g[tid * 4 + 1] + beta[tid * 4 + 1];
        float o2 = (v[2] - mean) * rstd * g[tid * 4 + 2] + beta[tid * 4 + 2];
        float o3 = (v[3] - mean) * rstd * g[tid * 4 + 3] + beta[tid * 4 + 3];
        o.x = cvt_pk_bf16(o0, o1);
        o.y = cvt_pk_bf16(o2, o3);
        *(uint2*)(outb + (size_t)row * 1024 + tid * 4) = o;
    } else {
        float4 o;
        o.x = ((v[0] - mean) * rstd * g[tid * 4 + 0] + beta[tid * 4 + 0]) * valid;
        o.y = ((v[1] - mean) * rstd * g[tid * 4 + 1] + beta[tid * 4 + 1]) * valid;
        o.z = ((v[2] - mean) * rstd * g[tid * 4 + 2] + beta[tid * 4 + 2]) * valid;
        o.w = ((v[3] - mean) * rstd * g[tid * 4 + 3] + beta[tid * 4 + 3]) * valid;
        *(float4*)(outf + (size_t)row * 1024 + tid * 4) = o;
    }
}

// ---------------------------------------------------------------------------
extern "C" void kernel_launch(void* const* d_in, const int* in_sizes, int n_in,
                              void* d_out, int out_size, void* d_ws, size_t ws_size,
                              hipStream_t stream)
{
    const float* x   = (const float*)d_in[0];
    const u8*    pad = (const u8*)d_in[1];
    const float* Wq  = (const float*)d_in[2];
    const float* Wk  = (const float*)d_in[3];
    const float* Wv  = (const float*)d_in[4];
    const float* W1  = (const float*)d_in[5];
    const float* b1  = (const float*)d_in[6];
    const float* W2  = (const float*)d_in[7];
    const float* b2  = (const float*)d_in[8];
    const float* g1  = (const float*)d_in[9];
    const float* be1 = (const float*)d_in[10];
    const float* g2  = (const float*)d_in[11];
    const float* be2 = (const float*)d_in[12];
    float* out = (float*)d_out;

    // workspace (~95 MB)
    u16* xb    = (u16*)d_ws;
    u16* Wqb   = xb    + 4194304;
    u16* Wkb   = Wqb   + 1048576;
    u16* Wvb   = Wkb   + 1048576;
    u16* W1b   = Wvb   + 1048576;
    u16* W2b   = W1b   + 1048576;
    u16* Qh    = W2b   + 1048576;        // [z][n][dh]
    u16* Kh    = Qh    + 4194304;        // [z][n][dh]
    u16* Vt    = Kh    + 4194304;        // [z][dh][n]  (km applied by vt_km)
    u16* hb    = Vt    + 4194304;        // LN1 output, bf16
    u16* ff1b  = hb    + 4194304;
    u16* ffb   = ff1b  + 4194304;        // FFN2 output, bf16
    u16* attnb = ffb   + 4194304;        // attention output, bf16
    float* km      = (float*)(attnb + 4194304);
    float* qm      = km      + 65536;
    float* partial = qm      + 65536;           // 4M f32
    float* invS    = partial + 4194304;         // 1M f32

    P5 p5;
    p5.in[0] = Wq; p5.in[1] = Wk; p5.in[2] = Wv; p5.in[3] = W1; p5.in[4] = W2;
    p5.out[0] = Wqb; p5.out[1] = Wkb; p5.out[2] = Wvb; p5.out[3] = W1b; p5.out[4] = W2b;
    cvt_all<<<9216, 256, 0, stream>>>(x, xb, p5);

    // Q/K (swapped, vectorized epilogue) and V (unswapped) projections
    gemm_qk<<<dim3(16, 32), 256, 0, stream>>>(xb, Wqb, Wkb, Qh, Kh);
    gemm_v<<<dim3(8, 32),  256, 0, stream>>>(xb, Wvb, Vt);

    rowmask2_bf<<<512, 256, 0, stream>>>(Kh, Qh, km, qm);
    vt_km<<<4096, 256, 0, stream>>>(Vt, km);

    attn_pass1<<<1024, 256, 0, stream>>>(Qh, Kh, km, partial);
    sum_inv<<<1024, 256, 0, stream>>>(partial, invS);
    attn_pass2<<<1024, 256, 0, stream>>>(Qh, Kh, Vt, qm, invS, pad, attnb);

    // h = LN(xb + attn) -> bf16 only
    ln_kernel<0><<<4096, 256, 0, stream>>>(xb, attnb, g1, be1, pad, nullptr, hb);

    // FFN (both outputs bf16)
    gemm_bt<2><<<dim3(16, 32), 256, 0, stream>>>(hb,   W1b, b1, ff1b);
    gemm_bt<3><<<dim3(16, 32), 256, 0, stream>>>(ff1b, W2b, b2, ffb);

    // out = LN(ff*valid + h) * valid  (final f32)
    ln_kernel<1><<<4096, 256, 0, stream>>>(ffb, hb, g2, be2, pad, out, nullptr);
}

// Round 16
// 174.534 us; speedup vs baseline: 1.1312x; 1.1052x over previous
//
#include <hip/hip_runtime.h>
#include <math.h>

typedef unsigned short u16;
typedef unsigned char  u8;
typedef unsigned int   u32;
typedef __attribute__((ext_vector_type(8))) short bf16x8;
typedef __attribute__((ext_vector_type(4))) float f32x4;

#define NSEQ   1024
#define DMODEL 1024
#define ZTOT   64
#define LOG2E  1.4426950408889634f

typedef const __attribute__((address_space(1))) void* gp1;
typedef __attribute__((address_space(3))) void* lp3;

__device__ __forceinline__ void gload16(const void* g, void* l) {
    __builtin_amdgcn_global_load_lds((gp1)g, (lp3)l, 16, 0, 0);
}

__device__ __forceinline__ u16 f2bf(float f) {
    u32 u = __builtin_bit_cast(u32, f);
    return (u16)((u + 0x7FFFu + ((u >> 16) & 1u)) >> 16);
}

__device__ __forceinline__ float bf2f(u32 lo16) {
    u32 t = lo16 << 16;
    return __builtin_bit_cast(float, t);
}

// HW packed f32->bf16 (RNE), 2 values -> 1 dword
__device__ __forceinline__ u32 cvt_pk_bf16(float a, float b) {
    u32 r;
    asm("v_cvt_pk_bf16_f32 %0, %1, %2" : "=v"(r) : "v"(a), "v"(b));
    return r;
}

// ---------------------------------------------------------------------------
// fp32 -> bf16 elementwise: x (4M elems) + 5 weights (1M each) in ONE launch.
// ---------------------------------------------------------------------------
struct P5 { const float* in[5]; u16* out[5]; };
__launch_bounds__(256)
__global__ void cvt_all(const float* __restrict__ x, u16* __restrict__ xb, P5 p) {
    int bid = blockIdx.x;
    const float* in;
    u16* out;
    int blk;
    if (bid < 4096) { in = x; out = xb; blk = bid; }
    else {
        int which = (bid - 4096) >> 10;
        blk = bid & 1023;
        in = p.in[which];
        out = p.out[which];
    }
    int i = (blk * 256 + threadIdx.x) * 4;
    float4 v = *(const float4*)(in + i);
    uint2 o;
    o.x = cvt_pk_bf16(v.x, v.y);
    o.y = cvt_pk_bf16(v.z, v.w);
    *(uint2*)(out + i) = o;
}

// sign(sum |row|) over 64 bf16 -> 0/1 ; grid 512: first half Kh->km, second Qh->qm
__launch_bounds__(256)
__global__ void rowmask2_bf(const u16* __restrict__ Kh, const u16* __restrict__ Qh,
                            float* __restrict__ km, float* __restrict__ qm) {
    int b = blockIdx.x;
    const u16* T = (b < 256) ? Kh : Qh;
    float* o = (b < 256) ? km : qm;
    int r = (b & 255) * 256 + threadIdx.x;
    const uint4* p = (const uint4*)(T + (size_t)r * 64);
    u32 acc = 0;
    #pragma unroll
    for (int i = 0; i < 8; i++) {
        uint4 q = p[i];
        acc |= (q.x | q.y | q.z | q.w) & 0x7fff7fffu;
    }
    o[r] = acc ? 1.f : 0.f;
}

// Vt[z][dh][tok] &= (km[z][tok] != 0)
__launch_bounds__(256)
__global__ void vt_km(u16* __restrict__ Vt, const float* __restrict__ km) {
    int idx = blockIdx.x * 256 + threadIdx.x;  // uint4 index (8 bf16)
    int e0 = idx * 8;
    int z = e0 >> 16;
    int tok = e0 & 1023;
    float4 ka = *(const float4*)(km + z * 1024 + tok);
    float4 kb = *(const float4*)(km + z * 1024 + tok + 4);
    uint4 v = *(uint4*)(Vt + e0);
    u32 m;
    m = (ka.x != 0.f ? 0x0000FFFFu : 0u) | (ka.y != 0.f ? 0xFFFF0000u : 0u); v.x &= m;
    m = (ka.z != 0.f ? 0x0000FFFFu : 0u) | (ka.w != 0.f ? 0xFFFF0000u : 0u); v.y &= m;
    m = (kb.x != 0.f ? 0x0000FFFFu : 0u) | (kb.y != 0.f ? 0xFFFF0000u : 0u); v.z &= m;
    m = (kb.z != 0.f ? 0x0000FFFFu : 0u) | (kb.w != 0.f ? 0xFFFF0000u : 0u); v.w &= m;
    *(uint4*)(Vt + e0) = v;
}

// ---------------------------------------------------------------------------
// Fused QKV projection GEMM, m97 structure: BM=BN=128, BK=32, 4 waves, 2-buf.
// grid (24, 32): bx>>3 selects {Q, K, V}.  (R11 exact)
// ---------------------------------------------------------------------------
__launch_bounds__(256)
__global__ void gemm_qkv(const u16* __restrict__ A,
                         const u16* __restrict__ Wq, const u16* __restrict__ Wk,
                         const u16* __restrict__ Wv,
                         u16* __restrict__ Qh, u16* __restrict__ Kh, u16* __restrict__ Vt)
{
    __shared__ __align__(16) u16 lA[2][128 * 32];
    __shared__ __align__(16) u16 lB[2][128 * 32];
    const int tid = threadIdx.x, lane = tid & 63, w = tid >> 6;
    const int frow = lane & 15, koct = lane >> 4;
    const int sel = blockIdx.x >> 3;
    const int col0 = (blockIdx.x & 7) * 128, row0 = blockIdx.y * 128;
    const u16* B = (sel == 0) ? Wq : (sel == 1) ? Wk : Wv;
    const int wrow = (w >> 1) * 64, wcol = (w & 1) * 64;
    f32x4 acc[4][4] = {};

    auto stage = [&](int buf, int k0) {
        #pragma unroll
        for (int i = 0; i < 2; i++) {
            int p = tid + i * 256;
            int row = p >> 2, sl = p & 3, ssl = sl ^ ((row >> 1) & 3);
            gload16(A + (size_t)(row0 + row) * 1024 + k0 + ssl * 8, (char*)lA[buf] + p * 16);
        }
        #pragma unroll
        for (int i = 0; i < 2; i++) {
            int p = tid + i * 256;
            int row = p >> 2, sl = p & 3, ssl = sl ^ ((row >> 1) & 3);
            gload16(B + (size_t)(col0 + row) * 1024 + k0 + ssl * 8, (char*)lB[buf] + p * 16);
        }
    };

    stage(0, 0);
    __syncthreads();
    int buf = 0;
    for (int k0 = 0; k0 < 1024; k0 += 32) {
        if (k0 + 32 < 1024) stage(buf ^ 1, k0 + 32);
        __builtin_amdgcn_s_setprio(1);
        bf16x8 af[4], bf[4];
        #pragma unroll
        for (int i = 0; i < 4; i++) {
            int r = wrow + i * 16 + frow;
            int sl = koct ^ ((r >> 1) & 3);
            af[i] = *(const bf16x8*)((const char*)lA[buf] + r * 64 + sl * 16);
        }
        #pragma unroll
        for (int j = 0; j < 4; j++) {
            int r = wcol + j * 16 + frow;
            int sl = koct ^ ((r >> 1) & 3);
            bf[j] = *(const bf16x8*)((const char*)lB[buf] + r * 64 + sl * 16);
        }
        #pragma unroll
        for (int i = 0; i < 4; i++)
            #pragma unroll
            for (int j = 0; j < 4; j++)
                acc[i][j] = __builtin_amdgcn_mfma_f32_16x16x32_bf16(af[i], bf[j], acc[i][j], 0, 0, 0);
        __builtin_amdgcn_s_setprio(0);
        __syncthreads();
        buf ^= 1;
    }

    if (sel < 2) {
        const float scale = (sel == 0) ? 0.125f * LOG2E : 1.0f;
        u16* outp = (sel == 0) ? Qh : Kh;
        #pragma unroll
        for (int i = 0; i < 4; i++)
            #pragma unroll
            for (int j = 0; j < 4; j++)
                #pragma unroll
                for (int q = 0; q < 4; q++) {
                    int r = row0 + wrow + i * 16 + koct * 4 + q;
                    int c = col0 + wcol + j * 16 + frow;
                    float v = acc[i][j][q] * scale;
                    outp[(size_t)((c >> 6) * 4 + (r >> 10)) * 65536 +
                         (size_t)(r & 1023) * 64 + (c & 63)] = f2bf(v);
                }
    } else {
        #pragma unroll
        for (int i = 0; i < 4; i++) {
            int r0 = row0 + wrow + i * 16 + koct * 4;   // token base (mult of 4)
            #pragma unroll
            for (int j = 0; j < 4; j++) {
                int c = col0 + wcol + j * 16 + frow;    // channel
                int z = (c >> 6) * 4 + (r0 >> 10);
                uint2 pk;
                pk.x = cvt_pk_bf16(acc[i][j][0], acc[i][j][1]);
                pk.y = cvt_pk_bf16(acc[i][j][2], acc[i][j][3]);
                *(uint2*)(Vt + (size_t)z * 65536 + (size_t)(c & 63) * 1024 + (r0 & 1023)) = pk;
            }
        }
    }
}

// ---------------------------------------------------------------------------
// bf16 MFMA GEMM for FFN, 2-buf, XCD-swizzled tile map (T1): XCD c owns a
// contiguous 64-tile chunk -> A 1MB + B 2MB per-XCD L2 working set.
// MODE 2: +bias+relu bf16. MODE 3: +bias bf16.
// ---------------------------------------------------------------------------
template <int MODE>
__launch_bounds__(256)
__global__ void gemm_bt(const u16* __restrict__ A, const u16* __restrict__ B,
                        const float* __restrict__ bias, u16* __restrict__ outp)
{
    __shared__ __align__(16) u16 lA[2][128 * 64];
    __shared__ __align__(16) u16 lB[2][64 * 64];
    const int tid = threadIdx.x, lane = tid & 63, w = tid >> 6;
    const int frow = lane & 15, koct = lane >> 4;
    // XCD swizzle: 512 blocks, dispatch round-robin id%8 = XCD; give XCD c
    // tiles [c*64, c*64+64) (4 row-panels x all 16 col-tiles).
    const int id = blockIdx.x;                       // 1-D grid 512
    const int tile = (id & 7) * 64 + (id >> 3);
    const int col0 = (tile & 15) * 64, row0 = (tile >> 4) * 128;
    const int wrow = (w >> 1) * 64, wcol = (w & 1) * 32;
    f32x4 acc[4][2] = {};

    auto stage = [&](int buf, int k0) {
        #pragma unroll
        for (int i = 0; i < 4; i++) {
            int p = tid + i * 256;
            int row = p >> 3, sl = p & 7, ssl = sl ^ (row & 7);
            gload16(A + (size_t)(row0 + row) * 1024 + k0 + ssl * 8, (char*)lA[buf] + p * 16);
        }
        #pragma unroll
        for (int i = 0; i < 2; i++) {
            int p = tid + i * 256;
            int row = p >> 3, sl = p & 7, ssl = sl ^ (row & 7);
            gload16(B + (size_t)(col0 + row) * 1024 + k0 + ssl * 8, (char*)lB[buf] + p * 16);
        }
    };

    stage(0, 0);
    __syncthreads();
    int buf = 0;
    for (int k0 = 0; k0 < 1024; k0 += 64) {
        if (k0 + 64 < 1024) stage(buf ^ 1, k0 + 64);
        __builtin_amdgcn_s_setprio(1);
        #pragma unroll
        for (int ks = 0; ks < 2; ks++) {
            bf16x8 af[4], bf2[2];
            #pragma unroll
            for (int i = 0; i < 4; i++) {
                int r = wrow + i * 16 + frow;
                int sl = (ks * 4 + koct) ^ (r & 7);
                af[i] = *(const bf16x8*)((const char*)lA[buf] + r * 128 + sl * 16);
            }
            #pragma unroll
            for (int j = 0; j < 2; j++) {
                int r = wcol + j * 16 + frow;
                int sl = (ks * 4 + koct) ^ (r & 7);
                bf2[j] = *(const bf16x8*)((const char*)lB[buf] + r * 128 + sl * 16);
            }
            #pragma unroll
            for (int i = 0; i < 4; i++)
                #pragma unroll
                for (int j = 0; j < 2; j++)
                    acc[i][j] = __builtin_amdgcn_mfma_f32_16x16x32_bf16(af[i], bf2[j], acc[i][j], 0, 0, 0);
        }
        __builtin_amdgcn_s_setprio(0);
        __syncthreads();
        buf ^= 1;
    }

    #pragma unroll
    for (int i = 0; i < 4; i++)
        #pragma unroll
        for (int j = 0; j < 2; j++)
            #pragma unroll
            for (int q = 0; q < 4; q++) {
                int r = row0 + wrow + i * 16 + koct * 4 + q;
                int c = col0 + wcol + j * 16 + frow;
                float v = acc[i][j][q] + bias[c];
                if constexpr (MODE == 2) v = fmaxf(v, 0.f);
                outp[(size_t)r * 1024 + c] = f2bf(v);
            }
}

// ---------------------------------------------------------------------------
// Pass 1: partial[zg][n][m] = sum_{z in zg*16..+16} exp2(s'_znm) * km01(z,m)
// 1-D grid 1024, XCD-swizzled: XCD c owns one zg x 8 m-tiles.
// ---------------------------------------------------------------------------
__launch_bounds__(256)
__global__ void attn_pass1(const u16* __restrict__ Qh, const u16* __restrict__ Kh,
                           const float* __restrict__ km, float* __restrict__ partial)
{
    const int bid = blockIdx.x;
    const int mtzg = (bid & 7) * 8 + ((bid >> 3) & 7);   // cluster per XCD
    const int m0 = (mtzg & 15) * 64, zg = mtzg >> 4;
    const int n0 = (bid >> 6) * 64;

    __shared__ __align__(16) u16 lQ[2][64 * 64];
    __shared__ __align__(16) u16 lK[2][64 * 64];
    const int tid = threadIdx.x, lane = tid & 63, w = tid >> 6;
    const int frow = lane & 15, koct = lane >> 4;
    const int wn = (w >> 1) * 32, wm = (w & 1) * 32;
    f32x4 ssum[2][2] = {};

    auto stage = [&](int buf, int z) {
        #pragma unroll
        for (int i = 0; i < 2; i++) {
            int p = tid + i * 256;
            int row = p >> 3, sl = p & 7, ssl = sl ^ (row & 7);
            gload16(Qh + (size_t)(z * NSEQ + n0 + row) * 64 + ssl * 8, (char*)lQ[buf] + p * 16);
            gload16(Kh + (size_t)(z * NSEQ + m0 + row) * 64 + ssl * 8, (char*)lK[buf] + p * 16);
        }
    };

    const int z0 = zg * 16;
    stage(0, z0);
    __syncthreads();
    int buf = 0;
    for (int zi = 0; zi < 16; zi++) {
        const int z = z0 + zi;
        if (zi < 15) stage(buf ^ 1, z + 1);
        f32x4 km4[2];
        #pragma unroll
        for (int j = 0; j < 2; j++)
            km4[j] = *(const f32x4*)(km + z * NSEQ + m0 + wm + j * 16 + koct * 4);
        f32x4 s[2][2] = {};
        __builtin_amdgcn_s_setprio(1);
        #pragma unroll
        for (int ks = 0; ks < 2; ks++) {
            bf16x8 a[2], b2[2];
            #pragma unroll
            for (int i = 0; i < 2; i++) {
                int r = wn + i * 16 + frow;
                int sl = (ks * 4 + koct) ^ (r & 7);
                a[i] = *(const bf16x8*)((const char*)lQ[buf] + r * 128 + sl * 16);
            }
            #pragma unroll
            for (int j = 0; j < 2; j++) {
                int r = wm + j * 16 + frow;
                int sl = (ks * 4 + koct) ^ (r & 7);
                b2[j] = *(const bf16x8*)((const char*)lK[buf] + r * 128 + sl * 16);
            }
            #pragma unroll
            for (int i = 0; i < 2; i++)
                #pragma unroll
                for (int j = 0; j < 2; j++)
                    s[i][j] = __builtin_amdgcn_mfma_f32_16x16x32_bf16(b2[j], a[i], s[i][j], 0, 0, 0);
        }
        __builtin_amdgcn_s_setprio(0);
        #pragma unroll
        for (int j = 0; j < 2; j++)
            #pragma unroll
            for (int i = 0; i < 2; i++)
                #pragma unroll
                for (int q = 0; q < 4; q++)
                    ssum[i][j][q] += __builtin_amdgcn_exp2f(s[i][j][q]) * km4[j][q];
        __syncthreads();
        buf ^= 1;
    }
    #pragma unroll
    for (int i = 0; i < 2; i++)
        #pragma unroll
        for (int j = 0; j < 2; j++) {
            int ng = n0 + wn + i * 16 + frow;
            int mg = m0 + wm + j * 16 + koct * 4;
            *(f32x4*)(partial + (size_t)zg * 1048576 + (size_t)ng * NSEQ + mg) = ssum[i][j];
        }
}

// invS = 1 / (p0+p1+p2+p3)
__launch_bounds__(256)
__global__ void sum_inv(const float* __restrict__ p, float* __restrict__ invS) {
    int i = (blockIdx.x * 256 + threadIdx.x) * 4;
    float4 a = *(const float4*)(p + i);
    float4 b = *(const float4*)(p + 1048576 + i);
    float4 c = *(const float4*)(p + 2097152 + i);
    float4 d = *(const float4*)(p + 3145728 + i);
    float4 r;
    float s;
    s = a.x + b.x + c.x + d.x; r.x = s > 0.f ? 1.f / s : 0.f;
    s = a.y + b.y + c.y + d.y; r.y = s > 0.f ? 1.f / s : 0.f;
    s = a.z + b.z + c.z + d.z; r.z = s > 0.f ? 1.f / s : 0.f;
    s = a.w + b.w + c.w + d.w; r.w = s > 0.f ? 1.f / s : 0.f;
    *(float4*)(invS + i) = r;
}

// ---------------------------------------------------------------------------
// Pass 2 (R7 structure, bf16 output): per z, out = sum_m (exp2(s')*invS) V'[m,:]
// m-tile 64, double-buffered staging, wave-private lP, 1 barrier per tile.
// grid 1024, XCD c owns z in {8c..8c+7}.
// ---------------------------------------------------------------------------
__launch_bounds__(256)
__global__ void attn_pass2(const u16* __restrict__ Qh, const u16* __restrict__ Kh,
                           const u16* __restrict__ Vt,
                           const float* __restrict__ qm, const float* __restrict__ invS,
                           const u8* __restrict__ pad, u16* __restrict__ attn)
{
    const int bid = blockIdx.x;
    const int z  = (bid & 7) * 8 + ((bid >> 3) & 7);     // cluster per XCD
    const int n0 = (bid >> 6) * 64;

    __shared__ __align__(16) u16 lK[2][64 * 64];
    __shared__ __align__(16) u16 lV[2][64 * 64];   // Vt tile: [d][m]
    __shared__ __align__(16) u16 lP[64 * 64];
    const int tid = threadIdx.x, lane = tid & 63, w = tid >> 6;
    const int frow = lane & 15, koct = lane >> 4;
    const int hh = z >> 2, bb = z & 3;
    const int wrow = w * 16;
    const int nl_row = wrow + frow;
    const size_t inv_base = (size_t)(n0 + nl_row) * NSEQ;

    bf16x8 aq[2];
    #pragma unroll
    for (int ks = 0; ks < 2; ks++)
        aq[ks] = *(const bf16x8*)(Qh + (size_t)(z * NSEQ + n0 + nl_row) * 64 + ks * 32 + koct * 8);

    auto stage = [&](int buf, int m0) {
        #pragma unroll
        for (int i = 0; i < 2; i++) {
            int p = tid + i * 256;
            int row = p >> 3, sl = p & 7, ssl = sl ^ (row & 7);
            gload16(Kh + (size_t)(z * NSEQ + m0 + row) * 64 + ssl * 8, (char*)lK[buf] + p * 16);
            gload16(Vt + (size_t)z * 65536 + (size_t)row * 1024 + m0 + ssl * 8, (char*)lV[buf] + p * 16);
        }
    };

    f32x4 oacc[4] = {};
    f32x4 iv[4];
    #pragma unroll
    for (int j = 0; j < 4; j++)
        iv[j] = *(const f32x4*)(invS + inv_base + j * 16 + koct * 4);
    stage(0, 0);
    __syncthreads();
    int buf = 0;

    for (int mt = 0; mt < 16; mt++) {
        const int m0 = mt * 64;
        if (mt < 15) stage(buf ^ 1, m0 + 64);
        f32x4 ivn[4];
        if (mt < 15) {
            #pragma unroll
            for (int j = 0; j < 4; j++)
                ivn[j] = *(const f32x4*)(invS + inv_base + m0 + 64 + j * 16 + koct * 4);
        }
        f32x4 s[4] = {};
        __builtin_amdgcn_s_setprio(1);
        #pragma unroll
        for (int ks = 0; ks < 2; ks++) {
            bf16x8 kb[4];
            #pragma unroll
            for (int j = 0; j < 4; j++) {
                int r = j * 16 + frow;
                int sl = (ks * 4 + koct) ^ (r & 7);
                kb[j] = *(const bf16x8*)((const char*)lK[buf] + r * 128 + sl * 16);
            }
            #pragma unroll
            for (int j = 0; j < 4; j++)
                s[j] = __builtin_amdgcn_mfma_f32_16x16x32_bf16(kb[j], aq[ks], s[j], 0, 0, 0);
        }
        __builtin_amdgcn_s_setprio(0);
        #pragma unroll
        for (int j = 0; j < 4; j++) {
            float p0 = __builtin_amdgcn_exp2f(s[j][0]) * iv[j][0];
            float p1 = __builtin_amdgcn_exp2f(s[j][1]) * iv[j][1];
            float p2 = __builtin_amdgcn_exp2f(s[j][2]) * iv[j][2];
            float p3 = __builtin_amdgcn_exp2f(s[j][3]) * iv[j][3];
            uint2 pk;
            pk.x = cvt_pk_bf16(p0, p1);
            pk.y = cvt_pk_bf16(p2, p3);
            int slot = (j * 2 + (koct >> 1)) ^ (nl_row & 7);
            *(uint2*)((char*)lP + nl_row * 128 + slot * 16 + (koct & 1) * 8) = pk;
        }
        __builtin_amdgcn_s_setprio(1);
        #pragma unroll
        for (int ks = 0; ks < 2; ks++) {
            int sl = (ks * 4 + koct) ^ (nl_row & 7);
            bf16x8 pa = *(const bf16x8*)((const char*)lP + nl_row * 128 + sl * 16);
            bf16x8 vb[4];
            #pragma unroll
            for (int dj = 0; dj < 4; dj++) {
                int rr = dj * 16 + frow;
                int sv = (ks * 4 + koct) ^ (rr & 7);
                vb[dj] = *(const bf16x8*)((const char*)lV[buf] + rr * 128 + sv * 16);
            }
            #pragma unroll
            for (int dj = 0; dj < 4; dj++)
                oacc[dj] = __builtin_amdgcn_mfma_f32_16x16x32_bf16(pa, vb[dj], oacc[dj], 0, 0, 0);
        }
        __builtin_amdgcn_s_setprio(0);
        __syncthreads();
        buf ^= 1;
        #pragma unroll
        for (int j = 0; j < 4; j++) iv[j] = ivn[j];
    }

    #pragma unroll
    for (int q = 0; q < 4; q++) {
        int ns = n0 + wrow + koct * 4 + q;
        float f = qm[z * NSEQ + ns] * (pad[bb * NSEQ + ns] ? 0.f : 1.f);
        #pragma unroll
        for (int dj = 0; dj < 4; dj++) {
            int d = dj * 16 + frow;
            attn[(size_t)(bb * NSEQ + ns) * DMODEL + hh * 64 + d] = f2bf(oacc[dj][q] * f);
        }
    }
}

// ---------------------------------------------------------------------------
// LayerNorm over last dim (1024), one block per row.
// MODE 0: A bf16 + B bf16 -> v = a+b ; out bf16 (hb) only.
// MODE 1: A bf16, B bf16 -> v = a*valid + b ; out f32 * valid (final).
// ---------------------------------------------------------------------------
template <int MODE>
__launch_bounds__(256)
__global__ void ln_kernel(const u16* __restrict__ Ap, const u16* __restrict__ Bp,
                          const float* __restrict__ g, const float* __restrict__ beta,
                          const u8* __restrict__ pad,
                          float* __restrict__ outf, u16* __restrict__ outb)
{
    const int row = blockIdx.x, tid = threadIdx.x;
    const int lane = tid & 63, wv = tid >> 6;
    const float valid = pad[row] ? 0.f : 1.f;
    __shared__ float red[4];

    uint2 aav = *(const uint2*)(Ap + (size_t)row * 1024 + tid * 4);
    uint2 bbv = *(const uint2*)(Bp + (size_t)row * 1024 + tid * 4);
    float v[4];
    if constexpr (MODE == 0) {
        v[0] = bf2f(aav.x & 0xFFFFu) + bf2f(bbv.x & 0xFFFFu);
        v[1] = bf2f(aav.x >> 16)     + bf2f(bbv.x >> 16);
        v[2] = bf2f(aav.y & 0xFFFFu) + bf2f(bbv.y & 0xFFFFu);
        v[3] = bf2f(aav.y >> 16)     + bf2f(bbv.y >> 16);
    } else {
        v[0] = bf2f(aav.x & 0xFFFFu) * valid + bf2f(bbv.x & 0xFFFFu);
        v[1] = bf2f(aav.x >> 16)     * valid + bf2f(bbv.x >> 16);
        v[2] = bf2f(aav.y & 0xFFFFu) * valid + bf2f(bbv.y & 0xFFFFu);
        v[3] = bf2f(aav.y >> 16)     * valid + bf2f(bbv.y >> 16);
    }
    float s = v[0] + v[1] + v[2] + v[3];
    #pragma unroll
    for (int off = 32; off > 0; off >>= 1) s += __shfl_down(s, off, 64);
    if (lane == 0) red[wv] = s;
    __syncthreads();
    float mean = (red[0] + red[1] + red[2] + red[3]) * (1.f / 1024.f);
    float sq = 0.f;
    #pragma unroll
    for (int k = 0; k < 4; k++) { float d = v[k] - mean; sq += d * d; }
    __syncthreads();
    #pragma unroll
    for (int off = 32; off > 0; off >>= 1) sq += __shfl_down(sq, off, 64);
    if (lane == 0) red[wv] = sq;
    __syncthreads();
    float var = (red[0] + red[1] + red[2] + red[3]) * (1.f / 1024.f);
    float rstd = rsqrtf(var + 1e-5f);

    if constexpr (MODE == 0) {
        uint2 o;
        float o0 = (v[0] - mean) * rstd * g[tid * 4 + 0] + beta[tid * 4 + 0];
        float o1 = (v[1] - mean) * rstd * g[tid * 4 + 1] + beta[tid * 4 + 1];
        float o2 = (v[2] - mean) * rstd * g[tid * 4 + 2] + beta[tid * 4 + 2];
        float o3 = (v[3] - mean) * rstd * g[tid * 4 + 3] + beta[tid * 4 + 3];
        o.x = cvt_pk_bf16(o0, o1);
        o.y = cvt_pk_bf16(o2, o3);
        *(uint2*)(outb + (size_t)row * 1024 + tid * 4) = o;
    } else {
        float4 o;
        o.x = ((v[0] - mean) * rstd * g[tid * 4 + 0] + beta[tid * 4 + 0]) * valid;
        o.y = ((v[1] - mean) * rstd * g[tid * 4 + 1] + beta[tid * 4 + 1]) * valid;
        o.z = ((v[2] - mean) * rstd * g[tid * 4 + 2] + beta[tid * 4 + 2]) * valid;
        o.w = ((v[3] - mean) * rstd * g[tid * 4 + 3] + beta[tid * 4 + 3]) * valid;
        *(float4*)(outf + (size_t)row * 1024 + tid * 4) = o;
    }
}

// ---------------------------------------------------------------------------
extern "C" void kernel_launch(void* const* d_in, const int* in_sizes, int n_in,
                              void* d_out, int out_size, void* d_ws, size_t ws_size,
                              hipStream_t stream)
{
    const float* x   = (const float*)d_in[0];
    const u8*    pad = (const u8*)d_in[1];
    const float* Wq  = (const float*)d_in[2];
    const float* Wk  = (const float*)d_in[3];
    const float* Wv  = (const float*)d_in[4];
    const float* W1  = (const float*)d_in[5];
    const float* b1  = (const float*)d_in[6];
    const float* W2  = (const float*)d_in[7];
    const float* b2  = (const float*)d_in[8];
    const float* g1  = (const float*)d_in[9];
    const float* be1 = (const float*)d_in[10];
    const float* g2  = (const float*)d_in[11];
    const float* be2 = (const float*)d_in[12];
    float* out = (float*)d_out;

    // workspace (~95 MB)
    u16* xb    = (u16*)d_ws;
    u16* Wqb   = xb    + 4194304;
    u16* Wkb   = Wqb   + 1048576;
    u16* Wvb   = Wkb   + 1048576;
    u16* W1b   = Wvb   + 1048576;
    u16* W2b   = W1b   + 1048576;
    u16* Qh    = W2b   + 1048576;        // [z][n][dh]
    u16* Kh    = Qh    + 4194304;        // [z][n][dh]
    u16* Vt    = Kh    + 4194304;        // [z][dh][n]  (km applied by vt_km)
    u16* hb    = Vt    + 4194304;        // LN1 output, bf16
    u16* ff1b  = hb    + 4194304;
    u16* ffb   = ff1b  + 4194304;        // FFN2 output, bf16
    u16* attnb = ffb   + 4194304;        // attention output, bf16
    float* km      = (float*)(attnb + 4194304);
    float* qm      = km      + 65536;
    float* partial = qm      + 65536;           // 4M f32
    float* invS    = partial + 4194304;         // 1M f32

    P5 p5;
    p5.in[0] = Wq; p5.in[1] = Wk; p5.in[2] = Wv; p5.in[3] = W1; p5.in[4] = W2;
    p5.out[0] = Wqb; p5.out[1] = Wkb; p5.out[2] = Wvb; p5.out[3] = W1b; p5.out[4] = W2b;
    cvt_all<<<9216, 256, 0, stream>>>(x, xb, p5);

    // fused Q/K/V projections, m97-structure 128x128 tiles (2-buf)  [R11]
    gemm_qkv<<<dim3(24, 32), 256, 0, stream>>>(xb, Wqb, Wkb, Wvb, Qh, Kh, Vt);

    rowmask2_bf<<<512, 256, 0, stream>>>(Kh, Qh, km, qm);
    vt_km<<<4096, 256, 0, stream>>>(Vt, km);

    attn_pass1<<<1024, 256, 0, stream>>>(Qh, Kh, km, partial);
    sum_inv<<<1024, 256, 0, stream>>>(partial, invS);
    attn_pass2<<<1024, 256, 0, stream>>>(Qh, Kh, Vt, qm, invS, pad, attnb);

    // h = LN(xb + attn) -> bf16 only
    ln_kernel<0><<<4096, 256, 0, stream>>>(xb, attnb, g1, be1, pad, nullptr, hb);

    // FFN (both outputs bf16, XCD-swizzled 1-D grids)
    gemm_bt<2><<<512, 256, 0, stream>>>(hb,   W1b, b1, ff1b);
    gemm_bt<3><<<512, 256, 0, stream>>>(ff1b, W2b, b2, ffb);

    // out = LN(ff*valid + h) * valid  (final f32)
    ln_kernel<1><<<4096, 256, 0, stream>>>(ffb, hb, g2, be2, pad, out, nullptr);
}

// Round 17
// 173.909 us; speedup vs baseline: 1.1353x; 1.0036x over previous
//
#include <hip/hip_runtime.h>
#include <math.h>

typedef unsigned short u16;
typedef unsigned char  u8;
typedef unsigned int   u32;
typedef __attribute__((ext_vector_type(8))) short bf16x8;
typedef __attribute__((ext_vector_type(4))) float f32x4;

#define NSEQ   1024
#define DMODEL 1024
#define ZTOT   64
#define LOG2E  1.4426950408889634f

typedef const __attribute__((address_space(1))) void* gp1;
typedef __attribute__((address_space(3))) void* lp3;

__device__ __forceinline__ void gload16(const void* g, void* l) {
    __builtin_amdgcn_global_load_lds((gp1)g, (lp3)l, 16, 0, 0);
}

__device__ __forceinline__ u16 f2bf(float f) {
    u32 u = __builtin_bit_cast(u32, f);
    return (u16)((u + 0x7FFFu + ((u >> 16) & 1u)) >> 16);
}

__device__ __forceinline__ float bf2f(u32 lo16) {
    u32 t = lo16 << 16;
    return __builtin_bit_cast(float, t);
}

// HW packed f32->bf16 (RNE), 2 values -> 1 dword
__device__ __forceinline__ u32 cvt_pk_bf16(float a, float b) {
    u32 r;
    asm("v_cvt_pk_bf16_f32 %0, %1, %2" : "=v"(r) : "v"(a), "v"(b));
    return r;
}

// ---------------------------------------------------------------------------
// fp32 -> bf16 elementwise: x (4M elems) + 5 weights (1M each) in ONE launch.
// ---------------------------------------------------------------------------
struct P5 { const float* in[5]; u16* out[5]; };
__launch_bounds__(256)
__global__ void cvt_all(const float* __restrict__ x, u16* __restrict__ xb, P5 p) {
    int bid = blockIdx.x;
    const float* in;
    u16* out;
    int blk;
    if (bid < 4096) { in = x; out = xb; blk = bid; }
    else {
        int which = (bid - 4096) >> 10;
        blk = bid & 1023;
        in = p.in[which];
        out = p.out[which];
    }
    int i = (blk * 256 + threadIdx.x) * 4;
    float4 v = *(const float4*)(in + i);
    uint2 o;
    o.x = cvt_pk_bf16(v.x, v.y);
    o.y = cvt_pk_bf16(v.z, v.w);
    *(uint2*)(out + i) = o;
}

// sign(sum |row|) over 64 bf16 -> 0/1 ; grid 512: first half Kh->km, second Qh->qm
__launch_bounds__(256)
__global__ void rowmask2_bf(const u16* __restrict__ Kh, const u16* __restrict__ Qh,
                            float* __restrict__ km, float* __restrict__ qm) {
    int b = blockIdx.x;
    const u16* T = (b < 256) ? Kh : Qh;
    float* o = (b < 256) ? km : qm;
    int r = (b & 255) * 256 + threadIdx.x;
    const uint4* p = (const uint4*)(T + (size_t)r * 64);
    u32 acc = 0;
    #pragma unroll
    for (int i = 0; i < 8; i++) {
        uint4 q = p[i];
        acc |= (q.x | q.y | q.z | q.w) & 0x7fff7fffu;
    }
    o[r] = acc ? 1.f : 0.f;
}

// Vt[z][dh][tok] &= (km[z][tok] != 0)
__launch_bounds__(256)
__global__ void vt_km(u16* __restrict__ Vt, const float* __restrict__ km) {
    int idx = blockIdx.x * 256 + threadIdx.x;  // uint4 index (8 bf16)
    int e0 = idx * 8;
    int z = e0 >> 16;
    int tok = e0 & 1023;
    float4 ka = *(const float4*)(km + z * 1024 + tok);
    float4 kb = *(const float4*)(km + z * 1024 + tok + 4);
    uint4 v = *(uint4*)(Vt + e0);
    u32 m;
    m = (ka.x != 0.f ? 0x0000FFFFu : 0u) | (ka.y != 0.f ? 0xFFFF0000u : 0u); v.x &= m;
    m = (ka.z != 0.f ? 0x0000FFFFu : 0u) | (ka.w != 0.f ? 0xFFFF0000u : 0u); v.y &= m;
    m = (kb.x != 0.f ? 0x0000FFFFu : 0u) | (kb.y != 0.f ? 0xFFFF0000u : 0u); v.z &= m;
    m = (kb.z != 0.f ? 0x0000FFFFu : 0u) | (kb.w != 0.f ? 0xFFFF0000u : 0u); v.w &= m;
    *(uint4*)(Vt + e0) = v;
}

// ---------------------------------------------------------------------------
// Fused QKV projection GEMM, m97 structure: BM=BN=128, BK=32, 4 waves, 2-buf.
// 1-D grid 768, chunked XCD swizzle: XCD c owns 4 contiguous row-panels x
// all (sel,col) -> per-XCD working set = 1MB A + streamed W (4-way L2 reuse).
// ---------------------------------------------------------------------------
__launch_bounds__(256)
__global__ void gemm_qkv(const u16* __restrict__ A,
                         const u16* __restrict__ Wq, const u16* __restrict__ Wk,
                         const u16* __restrict__ Wv,
                         u16* __restrict__ Qh, u16* __restrict__ Kh, u16* __restrict__ Vt)
{
    __shared__ __align__(16) u16 lA[2][128 * 32];
    __shared__ __align__(16) u16 lB[2][128 * 32];
    const int tid = threadIdx.x, lane = tid & 63, w = tid >> 6;
    const int frow = lane & 15, koct = lane >> 4;
    // XCD swizzle: id%8 = XCD; tile = (id%8)*96 + id/8; by-major decomposition
    const int id = blockIdx.x;
    const int tile = (id & 7) * 96 + (id >> 3);
    const int by = tile / 24;          // 0..31, contiguous per XCD chunk
    const int rem = tile % 24;
    const int sel = rem >> 3;
    const int col0 = (rem & 7) * 128, row0 = by * 128;
    const u16* B = (sel == 0) ? Wq : (sel == 1) ? Wk : Wv;
    const int wrow = (w >> 1) * 64, wcol = (w & 1) * 64;
    f32x4 acc[4][4] = {};

    auto stage = [&](int buf, int k0) {
        #pragma unroll
        for (int i = 0; i < 2; i++) {
            int p = tid + i * 256;
            int row = p >> 2, sl = p & 3, ssl = sl ^ ((row >> 1) & 3);
            gload16(A + (size_t)(row0 + row) * 1024 + k0 + ssl * 8, (char*)lA[buf] + p * 16);
        }
        #pragma unroll
        for (int i = 0; i < 2; i++) {
            int p = tid + i * 256;
            int row = p >> 2, sl = p & 3, ssl = sl ^ ((row >> 1) & 3);
            gload16(B + (size_t)(col0 + row) * 1024 + k0 + ssl * 8, (char*)lB[buf] + p * 16);
        }
    };

    stage(0, 0);
    __syncthreads();
    int buf = 0;
    for (int k0 = 0; k0 < 1024; k0 += 32) {
        if (k0 + 32 < 1024) stage(buf ^ 1, k0 + 32);
        __builtin_amdgcn_s_setprio(1);
        bf16x8 af[4], bf[4];
        #pragma unroll
        for (int i = 0; i < 4; i++) {
            int r = wrow + i * 16 + frow;
            int sl = koct ^ ((r >> 1) & 3);
            af[i] = *(const bf16x8*)((const char*)lA[buf] + r * 64 + sl * 16);
        }
        #pragma unroll
        for (int j = 0; j < 4; j++) {
            int r = wcol + j * 16 + frow;
            int sl = koct ^ ((r >> 1) & 3);
            bf[j] = *(const bf16x8*)((const char*)lB[buf] + r * 64 + sl * 16);
        }
        #pragma unroll
        for (int i = 0; i < 4; i++)
            #pragma unroll
            for (int j = 0; j < 4; j++)
                acc[i][j] = __builtin_amdgcn_mfma_f32_16x16x32_bf16(af[i], bf[j], acc[i][j], 0, 0, 0);
        __builtin_amdgcn_s_setprio(0);
        __syncthreads();
        buf ^= 1;
    }

    if (sel < 2) {
        const float scale = (sel == 0) ? 0.125f * LOG2E : 1.0f;
        u16* outp = (sel == 0) ? Qh : Kh;
        #pragma unroll
        for (int i = 0; i < 4; i++)
            #pragma unroll
            for (int j = 0; j < 4; j++)
                #pragma unroll
                for (int q = 0; q < 4; q++) {
                    int r = row0 + wrow + i * 16 + koct * 4 + q;
                    int c = col0 + wcol + j * 16 + frow;
                    float v = acc[i][j][q] * scale;
                    outp[(size_t)((c >> 6) * 4 + (r >> 10)) * 65536 +
                         (size_t)(r & 1023) * 64 + (c & 63)] = f2bf(v);
                }
    } else {
        #pragma unroll
        for (int i = 0; i < 4; i++) {
            int r0 = row0 + wrow + i * 16 + koct * 4;   // token base (mult of 4)
            #pragma unroll
            for (int j = 0; j < 4; j++) {
                int c = col0 + wcol + j * 16 + frow;    // channel
                int z = (c >> 6) * 4 + (r0 >> 10);
                uint2 pk;
                pk.x = cvt_pk_bf16(acc[i][j][0], acc[i][j][1]);
                pk.y = cvt_pk_bf16(acc[i][j][2], acc[i][j][3]);
                *(uint2*)(Vt + (size_t)z * 65536 + (size_t)(c & 63) * 1024 + (r0 & 1023)) = pk;
            }
        }
    }
}

// ---------------------------------------------------------------------------
// bf16 MFMA GEMM for FFN, 2-buf, XCD-swizzled tile map (T1): XCD c owns a
// contiguous 64-tile chunk -> A 1MB + B 2MB per-XCD L2 working set.
// MODE 2: +bias+relu bf16. MODE 3: +bias bf16.
// ---------------------------------------------------------------------------
template <int MODE>
__launch_bounds__(256)
__global__ void gemm_bt(const u16* __restrict__ A, const u16* __restrict__ B,
                        const float* __restrict__ bias, u16* __restrict__ outp)
{
    __shared__ __align__(16) u16 lA[2][128 * 64];
    __shared__ __align__(16) u16 lB[2][64 * 64];
    const int tid = threadIdx.x, lane = tid & 63, w = tid >> 6;
    const int frow = lane & 15, koct = lane >> 4;
    const int id = blockIdx.x;                       // 1-D grid 512
    const int tile = (id & 7) * 64 + (id >> 3);
    const int col0 = (tile & 15) * 64, row0 = (tile >> 4) * 128;
    const int wrow = (w >> 1) * 64, wcol = (w & 1) * 32;
    f32x4 acc[4][2] = {};

    auto stage = [&](int buf, int k0) {
        #pragma unroll
        for (int i = 0; i < 4; i++) {
            int p = tid + i * 256;
            int row = p >> 3, sl = p & 7, ssl = sl ^ (row & 7);
            gload16(A + (size_t)(row0 + row) * 1024 + k0 + ssl * 8, (char*)lA[buf] + p * 16);
        }
        #pragma unroll
        for (int i = 0; i < 2; i++) {
            int p = tid + i * 256;
            int row = p >> 3, sl = p & 7, ssl = sl ^ (row & 7);
            gload16(B + (size_t)(col0 + row) * 1024 + k0 + ssl * 8, (char*)lB[buf] + p * 16);
        }
    };

    stage(0, 0);
    __syncthreads();
    int buf = 0;
    for (int k0 = 0; k0 < 1024; k0 += 64) {
        if (k0 + 64 < 1024) stage(buf ^ 1, k0 + 64);
        __builtin_amdgcn_s_setprio(1);
        #pragma unroll
        for (int ks = 0; ks < 2; ks++) {
            bf16x8 af[4], bf2[2];
            #pragma unroll
            for (int i = 0; i < 4; i++) {
                int r = wrow + i * 16 + frow;
                int sl = (ks * 4 + koct) ^ (r & 7);
                af[i] = *(const bf16x8*)((const char*)lA[buf] + r * 128 + sl * 16);
            }
            #pragma unroll
            for (int j = 0; j < 2; j++) {
                int r = wcol + j * 16 + frow;
                int sl = (ks * 4 + koct) ^ (r & 7);
                bf2[j] = *(const bf16x8*)((const char*)lB[buf] + r * 128 + sl * 16);
            }
            #pragma unroll
            for (int i = 0; i < 4; i++)
                #pragma unroll
                for (int j = 0; j < 2; j++)
                    acc[i][j] = __builtin_amdgcn_mfma_f32_16x16x32_bf16(af[i], bf2[j], acc[i][j], 0, 0, 0);
        }
        __builtin_amdgcn_s_setprio(0);
        __syncthreads();
        buf ^= 1;
    }

    #pragma unroll
    for (int i = 0; i < 4; i++)
        #pragma unroll
        for (int j = 0; j < 2; j++)
            #pragma unroll
            for (int q = 0; q < 4; q++) {
                int r = row0 + wrow + i * 16 + koct * 4 + q;
                int c = col0 + wcol + j * 16 + frow;
                float v = acc[i][j][q] + bias[c];
                if constexpr (MODE == 2) v = fmaxf(v, 0.f);
                outp[(size_t)r * 1024 + c] = f2bf(v);
            }
}

// ---------------------------------------------------------------------------
// Pass 1: partial[zg][n][m] = sum_{z in zg*16..+16} exp2(s'_znm) * km01(z,m)
// 1-D grid 1024, XCD-swizzled: XCD c owns one zg x 8 m-tiles.
// ---------------------------------------------------------------------------
__launch_bounds__(256)
__global__ void attn_pass1(const u16* __restrict__ Qh, const u16* __restrict__ Kh,
                           const float* __restrict__ km, float* __restrict__ partial)
{
    const int bid = blockIdx.x;
    const int mtzg = (bid & 7) * 8 + ((bid >> 3) & 7);   // cluster per XCD
    const int m0 = (mtzg & 15) * 64, zg = mtzg >> 4;
    const int n0 = (bid >> 6) * 64;

    __shared__ __align__(16) u16 lQ[2][64 * 64];
    __shared__ __align__(16) u16 lK[2][64 * 64];
    const int tid = threadIdx.x, lane = tid & 63, w = tid >> 6;
    const int frow = lane & 15, koct = lane >> 4;
    const int wn = (w >> 1) * 32, wm = (w & 1) * 32;
    f32x4 ssum[2][2] = {};

    auto stage = [&](int buf, int z) {
        #pragma unroll
        for (int i = 0; i < 2; i++) {
            int p = tid + i * 256;
            int row = p >> 3, sl = p & 7, ssl = sl ^ (row & 7);
            gload16(Qh + (size_t)(z * NSEQ + n0 + row) * 64 + ssl * 8, (char*)lQ[buf] + p * 16);
            gload16(Kh + (size_t)(z * NSEQ + m0 + row) * 64 + ssl * 8, (char*)lK[buf] + p * 16);
        }
    };

    const int z0 = zg * 16;
    stage(0, z0);
    __syncthreads();
    int buf = 0;
    for (int zi = 0; zi < 16; zi++) {
        const int z = z0 + zi;
        if (zi < 15) stage(buf ^ 1, z + 1);
        f32x4 km4[2];
        #pragma unroll
        for (int j = 0; j < 2; j++)
            km4[j] = *(const f32x4*)(km + z * NSEQ + m0 + wm + j * 16 + koct * 4);
        f32x4 s[2][2] = {};
        __builtin_amdgcn_s_setprio(1);
        #pragma unroll
        for (int ks = 0; ks < 2; ks++) {
            bf16x8 a[2], b2[2];
            #pragma unroll
            for (int i = 0; i < 2; i++) {
                int r = wn + i * 16 + frow;
                int sl = (ks * 4 + koct) ^ (r & 7);
                a[i] = *(const bf16x8*)((const char*)lQ[buf] + r * 128 + sl * 16);
            }
            #pragma unroll
            for (int j = 0; j < 2; j++) {
                int r = wm + j * 16 + frow;
                int sl = (ks * 4 + koct) ^ (r & 7);
                b2[j] = *(const bf16x8*)((const char*)lK[buf] + r * 128 + sl * 16);
            }
            #pragma unroll
            for (int i = 0; i < 2; i++)
                #pragma unroll
                for (int j = 0; j < 2; j++)
                    s[i][j] = __builtin_amdgcn_mfma_f32_16x16x32_bf16(b2[j], a[i], s[i][j], 0, 0, 0);
        }
        __builtin_amdgcn_s_setprio(0);
        #pragma unroll
        for (int j = 0; j < 2; j++)
            #pragma unroll
            for (int i = 0; i < 2; i++)
                #pragma unroll
                for (int q = 0; q < 4; q++)
                    ssum[i][j][q] += __builtin_amdgcn_exp2f(s[i][j][q]) * km4[j][q];
        __syncthreads();
        buf ^= 1;
    }
    #pragma unroll
    for (int i = 0; i < 2; i++)
        #pragma unroll
        for (int j = 0; j < 2; j++) {
            int ng = n0 + wn + i * 16 + frow;
            int mg = m0 + wm + j * 16 + koct * 4;
            *(f32x4*)(partial + (size_t)zg * 1048576 + (size_t)ng * NSEQ + mg) = ssum[i][j];
        }
}

// invS = 1 / (p0+p1+p2+p3)
__launch_bounds__(256)
__global__ void sum_inv(const float* __restrict__ p, float* __restrict__ invS) {
    int i = (blockIdx.x * 256 + threadIdx.x) * 4;
    float4 a = *(const float4*)(p + i);
    float4 b = *(const float4*)(p + 1048576 + i);
    float4 c = *(const float4*)(p + 2097152 + i);
    float4 d = *(const float4*)(p + 3145728 + i);
    float4 r;
    float s;
    s = a.x + b.x + c.x + d.x; r.x = s > 0.f ? 1.f / s : 0.f;
    s = a.y + b.y + c.y + d.y; r.y = s > 0.f ? 1.f / s : 0.f;
    s = a.z + b.z + c.z + d.z; r.z = s > 0.f ? 1.f / s : 0.f;
    s = a.w + b.w + c.w + d.w; r.w = s > 0.f ? 1.f / s : 0.f;
    *(float4*)(invS + i) = r;
}

// ---------------------------------------------------------------------------
// Pass 2 (R7 structure, bf16 output): per z, out = sum_m (exp2(s')*invS) V'[m,:]
// m-tile 64, double-buffered staging, wave-private lP, 1 barrier per tile.
// grid 1024, XCD c owns z in {8c..8c+7}.
// ---------------------------------------------------------------------------
__launch_bounds__(256)
__global__ void attn_pass2(const u16* __restrict__ Qh, const u16* __restrict__ Kh,
                           const u16* __restrict__ Vt,
                           const float* __restrict__ qm, const float* __restrict__ invS,
                           const u8* __restrict__ pad, u16* __restrict__ attn)
{
    const int bid = blockIdx.x;
    const int z  = (bid & 7) * 8 + ((bid >> 3) & 7);     // cluster per XCD
    const int n0 = (bid >> 6) * 64;

    __shared__ __align__(16) u16 lK[2][64 * 64];
    __shared__ __align__(16) u16 lV[2][64 * 64];   // Vt tile: [d][m]
    __shared__ __align__(16) u16 lP[64 * 64];
    const int tid = threadIdx.x, lane = tid & 63, w = tid >> 6;
    const int frow = lane & 15, koct = lane >> 4;
    const int hh = z >> 2, bb = z & 3;
    const int wrow = w * 16;
    const int nl_row = wrow + frow;
    const size_t inv_base = (size_t)(n0 + nl_row) * NSEQ;

    bf16x8 aq[2];
    #pragma unroll
    for (int ks = 0; ks < 2; ks++)
        aq[ks] = *(const bf16x8*)(Qh + (size_t)(z * NSEQ + n0 + nl_row) * 64 + ks * 32 + koct * 8);

    auto stage = [&](int buf, int m0) {
        #pragma unroll
        for (int i = 0; i < 2; i++) {
            int p = tid + i * 256;
            int row = p >> 3, sl = p & 7, ssl = sl ^ (row & 7);
            gload16(Kh + (size_t)(z * NSEQ + m0 + row) * 64 + ssl * 8, (char*)lK[buf] + p * 16);
            gload16(Vt + (size_t)z * 65536 + (size_t)row * 1024 + m0 + ssl * 8, (char*)lV[buf] + p * 16);
        }
    };

    f32x4 oacc[4] = {};
    f32x4 iv[4];
    #pragma unroll
    for (int j = 0; j < 4; j++)
        iv[j] = *(const f32x4*)(invS + inv_base + j * 16 + koct * 4);
    stage(0, 0);
    __syncthreads();
    int buf = 0;

    for (int mt = 0; mt < 16; mt++) {
        const int m0 = mt * 64;
        if (mt < 15) stage(buf ^ 1, m0 + 64);
        f32x4 ivn[4];
        if (mt < 15) {
            #pragma unroll
            for (int j = 0; j < 4; j++)
                ivn[j] = *(const f32x4*)(invS + inv_base + m0 + 64 + j * 16 + koct * 4);
        }
        f32x4 s[4] = {};
        __builtin_amdgcn_s_setprio(1);
        #pragma unroll
        for (int ks = 0; ks < 2; ks++) {
            bf16x8 kb[4];
            #pragma unroll
            for (int j = 0; j < 4; j++) {
                int r = j * 16 + frow;
                int sl = (ks * 4 + koct) ^ (r & 7);
                kb[j] = *(const bf16x8*)((const char*)lK[buf] + r * 128 + sl * 16);
            }
            #pragma unroll
            for (int j = 0; j < 4; j++)
                s[j] = __builtin_amdgcn_mfma_f32_16x16x32_bf16(kb[j], aq[ks], s[j], 0, 0, 0);
        }
        __builtin_amdgcn_s_setprio(0);
        #pragma unroll
        for (int j = 0; j < 4; j++) {
            float p0 = __builtin_amdgcn_exp2f(s[j][0]) * iv[j][0];
            float p1 = __builtin_amdgcn_exp2f(s[j][1]) * iv[j][1];
            float p2 = __builtin_amdgcn_exp2f(s[j][2]) * iv[j][2];
            float p3 = __builtin_amdgcn_exp2f(s[j][3]) * iv[j][3];
            uint2 pk;
            pk.x = cvt_pk_bf16(p0, p1);
            pk.y = cvt_pk_bf16(p2, p3);
            int slot = (j * 2 + (koct >> 1)) ^ (nl_row & 7);
            *(uint2*)((char*)lP + nl_row * 128 + slot * 16 + (koct & 1) * 8) = pk;
        }
        __builtin_amdgcn_s_setprio(1);
        #pragma unroll
        for (int ks = 0; ks < 2; ks++) {
            int sl = (ks * 4 + koct) ^ (nl_row & 7);
            bf16x8 pa = *(const bf16x8*)((const char*)lP + nl_row * 128 + sl * 16);
            bf16x8 vb[4];
            #pragma unroll
            for (int dj = 0; dj < 4; dj++) {
                int rr = dj * 16 + frow;
                int sv = (ks * 4 + koct) ^ (rr & 7);
                vb[dj] = *(const bf16x8*)((const char*)lV[buf] + rr * 128 + sv * 16);
            }
            #pragma unroll
            for (int dj = 0; dj < 4; dj++)
                oacc[dj] = __builtin_amdgcn_mfma_f32_16x16x32_bf16(pa, vb[dj], oacc[dj], 0, 0, 0);
        }
        __builtin_amdgcn_s_setprio(0);
        __syncthreads();
        buf ^= 1;
        #pragma unroll
        for (int j = 0; j < 4; j++) iv[j] = ivn[j];
    }

    #pragma unroll
    for (int q = 0; q < 4; q++) {
        int ns = n0 + wrow + koct * 4 + q;
        float f = qm[z * NSEQ + ns] * (pad[bb * NSEQ + ns] ? 0.f : 1.f);
        #pragma unroll
        for (int dj = 0; dj < 4; dj++) {
            int d = dj * 16 + frow;
            attn[(size_t)(bb * NSEQ + ns) * DMODEL + hh * 64 + d] = f2bf(oacc[dj][q] * f);
        }
    }
}

// ---------------------------------------------------------------------------
// LayerNorm over last dim (1024), one block per row.
// MODE 0: A bf16 + B bf16 -> v = a+b ; out bf16 (hb) only.
// MODE 1: A bf16, B bf16 -> v = a*valid + b ; out f32 * valid (final).
// ---------------------------------------------------------------------------
template <int MODE>
__launch_bounds__(256)
__global__ void ln_kernel(const u16* __restrict__ Ap, const u16* __restrict__ Bp,
                          const float* __restrict__ g, const float* __restrict__ beta,
                          const u8* __restrict__ pad,
                          float* __restrict__ outf, u16* __restrict__ outb)
{
    const int row = blockIdx.x, tid = threadIdx.x;
    const int lane = tid & 63, wv = tid >> 6;
    const float valid = pad[row] ? 0.f : 1.f;
    __shared__ float red[4];

    uint2 aav = *(const uint2*)(Ap + (size_t)row * 1024 + tid * 4);
    uint2 bbv = *(const uint2*)(Bp + (size_t)row * 1024 + tid * 4);
    float v[4];
    if constexpr (MODE == 0) {
        v[0] = bf2f(aav.x & 0xFFFFu) + bf2f(bbv.x & 0xFFFFu);
        v[1] = bf2f(aav.x >> 16)     + bf2f(bbv.x >> 16);
        v[2] = bf2f(aav.y & 0xFFFFu) + bf2f(bbv.y & 0xFFFFu);
        v[3] = bf2f(aav.y >> 16)     + bf2f(bbv.y >> 16);
    } else {
        v[0] = bf2f(aav.x & 0xFFFFu) * valid + bf2f(bbv.x & 0xFFFFu);
        v[1] = bf2f(aav.x >> 16)     * valid + bf2f(bbv.x >> 16);
        v[2] = bf2f(aav.y & 0xFFFFu) * valid + bf2f(bbv.y & 0xFFFFu);
        v[3] = bf2f(aav.y >> 16)     * valid + bf2f(bbv.y >> 16);
    }
    float s = v[0] + v[1] + v[2] + v[3];
    #pragma unroll
    for (int off = 32; off > 0; off >>= 1) s += __shfl_down(s, off, 64);
    if (lane == 0) red[wv] = s;
    __syncthreads();
    float mean = (red[0] + red[1] + red[2] + red[3]) * (1.f / 1024.f);
    float sq = 0.f;
    #pragma unroll
    for (int k = 0; k < 4; k++) { float d = v[k] - mean; sq += d * d; }
    __syncthreads();
    #pragma unroll
    for (int off = 32; off > 0; off >>= 1) sq += __shfl_down(sq, off, 64);
    if (lane == 0) red[wv] = sq;
    __syncthreads();
    float var = (red[0] + red[1] + red[2] + red[3]) * (1.f / 1024.f);
    float rstd = rsqrtf(var + 1e-5f);

    if constexpr (MODE == 0) {
        uint2 o;
        float o0 = (v[0] - mean) * rstd * g[tid * 4 + 0] + beta[tid * 4 + 0];
        float o1 = (v[1] - mean) * rstd * g[tid * 4 + 1] + beta[tid * 4 + 1];
        float o2 = (v[2] - mean) * rstd * g[tid * 4 + 2] + beta[tid * 4 + 2];
        float o3 = (v[3] - mean) * rstd * g[tid * 4 + 3] + beta[tid * 4 + 3];
        o.x = cvt_pk_bf16(o0, o1);
        o.y = cvt_pk_bf16(o2, o3);
        *(uint2*)(outb + (size_t)row * 1024 + tid * 4) = o;
    } else {
        float4 o;
        o.x = ((v[0] - mean) * rstd * g[tid * 4 + 0] + beta[tid * 4 + 0]) * valid;
        o.y = ((v[1] - mean) * rstd * g[tid * 4 + 1] + beta[tid * 4 + 1]) * valid;
        o.z = ((v[2] - mean) * rstd * g[tid * 4 + 2] + beta[tid * 4 + 2]) * valid;
        o.w = ((v[3] - mean) * rstd * g[tid * 4 + 3] + beta[tid * 4 + 3]) * valid;
        *(float4*)(outf + (size_t)row * 1024 + tid * 4) = o;
    }
}

// ---------------------------------------------------------------------------
extern "C" void kernel_launch(void* const* d_in, const int* in_sizes, int n_in,
                              void* d_out, int out_size, void* d_ws, size_t ws_size,
                              hipStream_t stream)
{
    const float* x   = (const float*)d_in[0];
    const u8*    pad = (const u8*)d_in[1];
    const float* Wq  = (const float*)d_in[2];
    const float* Wk  = (const float*)d_in[3];
    const float* Wv  = (const float*)d_in[4];
    const float* W1  = (const float*)d_in[5];
    const float* b1  = (const float*)d_in[6];
    const float* W2  = (const float*)d_in[7];
    const float* b2  = (const float*)d_in[8];
    const float* g1  = (const float*)d_in[9];
    const float* be1 = (const float*)d_in[10];
    const float* g2  = (const float*)d_in[11];
    const float* be2 = (const float*)d_in[12];
    float* out = (float*)d_out;

    // workspace (~95 MB)
    u16* xb    = (u16*)d_ws;
    u16* Wqb   = xb    + 4194304;
    u16* Wkb   = Wqb   + 1048576;
    u16* Wvb   = Wkb   + 1048576;
    u16* W1b   = Wvb   + 1048576;
    u16* W2b   = W1b   + 1048576;
    u16* Qh    = W2b   + 1048576;        // [z][n][dh]
    u16* Kh    = Qh    + 4194304;        // [z][n][dh]
    u16* Vt    = Kh    + 4194304;        // [z][dh][n]  (km applied by vt_km)
    u16* hb    = Vt    + 4194304;        // LN1 output, bf16
    u16* ff1b  = hb    + 4194304;
    u16* ffb   = ff1b  + 4194304;        // FFN2 output, bf16
    u16* attnb = ffb   + 4194304;        // attention output, bf16
    float* km      = (float*)(attnb + 4194304);
    float* qm      = km      + 65536;
    float* partial = qm      + 65536;           // 4M f32
    float* invS    = partial + 4194304;         // 1M f32

    P5 p5;
    p5.in[0] = Wq; p5.in[1] = Wk; p5.in[2] = Wv; p5.in[3] = W1; p5.in[4] = W2;
    p5.out[0] = Wqb; p5.out[1] = Wkb; p5.out[2] = Wvb; p5.out[3] = W1b; p5.out[4] = W2b;
    cvt_all<<<9216, 256, 0, stream>>>(x, xb, p5);

    // fused Q/K/V projections, chunked XCD swizzle (1-D grid 768)
    gemm_qkv<<<768, 256, 0, stream>>>(xb, Wqb, Wkb, Wvb, Qh, Kh, Vt);

    rowmask2_bf<<<512, 256, 0, stream>>>(Kh, Qh, km, qm);
    vt_km<<<4096, 256, 0, stream>>>(Vt, km);

    attn_pass1<<<1024, 256, 0, stream>>>(Qh, Kh, km, partial);
    sum_inv<<<1024, 256, 0, stream>>>(partial, invS);
    attn_pass2<<<1024, 256, 0, stream>>>(Qh, Kh, Vt, qm, invS, pad, attnb);

    // h = LN(xb + attn) -> bf16 only
    ln_kernel<0><<<4096, 256, 0, stream>>>(xb, attnb, g1, be1, pad, nullptr, hb);

    // FFN (both outputs bf16, XCD-swizzled 1-D grids)
    gemm_bt<2><<<512, 256, 0, stream>>>(hb,   W1b, b1, ff1b);
    gemm_bt<3><<<512, 256, 0, stream>>>(ff1b, W2b, b2, ffb);

    // out = LN(ff*valid + h) * valid  (final f32)
    ln_kernel<1><<<4096, 256, 0, stream>>>(ffb, hb, g2, be2, pad, out, nullptr);
}

// Round 18
// 168.412 us; speedup vs baseline: 1.1723x; 1.0326x over previous
//
#include <hip/hip_runtime.h>
#include <math.h>

typedef unsigned short u16;
typedef unsigned char  u8;
typedef unsigned int   u32;
typedef __attribute__((ext_vector_type(8))) short bf16x8;
typedef __attribute__((ext_vector_type(4))) float f32x4;

#define NSEQ   1024
#define DMODEL 1024
#define ZTOT   64
#define LOG2E  1.4426950408889634f

typedef const __attribute__((address_space(1))) void* gp1;
typedef __attribute__((address_space(3))) void* lp3;

__device__ __forceinline__ void gload16(const void* g, void* l) {
    __builtin_amdgcn_global_load_lds((gp1)g, (lp3)l, 16, 0, 0);
}

__device__ __forceinline__ u16 f2bf(float f) {
    u32 u = __builtin_bit_cast(u32, f);
    return (u16)((u + 0x7FFFu + ((u >> 16) & 1u)) >> 16);
}

__device__ __forceinline__ float bf2f(u32 lo16) {
    u32 t = lo16 << 16;
    return __builtin_bit_cast(float, t);
}

// HW packed f32->bf16 (RNE), 2 values -> 1 dword
__device__ __forceinline__ u32 cvt_pk_bf16(float a, float b) {
    u32 r;
    asm("v_cvt_pk_bf16_f32 %0, %1, %2" : "=v"(r) : "v"(a), "v"(b));
    return r;
}

// ---------------------------------------------------------------------------
// fp32 -> bf16 elementwise: x (4M elems) + 5 weights (1M each) in ONE launch.
// ---------------------------------------------------------------------------
struct P5 { const float* in[5]; u16* out[5]; };
__launch_bounds__(256)
__global__ void cvt_all(const float* __restrict__ x, u16* __restrict__ xb, P5 p) {
    int bid = blockIdx.x;
    const float* in;
    u16* out;
    int blk;
    if (bid < 4096) { in = x; out = xb; blk = bid; }
    else {
        int which = (bid - 4096) >> 10;
        blk = bid & 1023;
        in = p.in[which];
        out = p.out[which];
    }
    int i = (blk * 256 + threadIdx.x) * 4;
    float4 v = *(const float4*)(in + i);
    uint2 o;
    o.x = cvt_pk_bf16(v.x, v.y);
    o.y = cvt_pk_bf16(v.z, v.w);
    *(uint2*)(out + i) = o;
}

// ---------------------------------------------------------------------------
// Fused masks: blocks 0..255: km = sign(sum|Kh row|), and zero Vt[z][:,tok]
// where km == 0 (rare path, exec-mask skipped when no lane triggers).
// Blocks 256..511: qm from Qh. Bitwise-identical to rowmask + vt_km.
// ---------------------------------------------------------------------------
__launch_bounds__(256)
__global__ void rowmask_fused(const u16* __restrict__ Kh, const u16* __restrict__ Qh,
                              u16* __restrict__ Vt,
                              float* __restrict__ km, float* __restrict__ qm) {
    int b = blockIdx.x;
    if (b < 256) {
        int r = b * 256 + threadIdx.x;          // r = z*1024 + tok
        const uint4* p = (const uint4*)(Kh + (size_t)r * 64);
        u32 acc = 0;
        #pragma unroll
        for (int i = 0; i < 8; i++) {
            uint4 q = p[i];
            acc |= (q.x | q.y | q.z | q.w) & 0x7fff7fffu;
        }
        km[r] = acc ? 1.f : 0.f;
        if (!acc) {                             // km==0: zero V column (rare)
            int z = r >> 10, tok = r & 1023;
            u16* col = Vt + (size_t)z * 65536 + tok;
            #pragma unroll
            for (int d = 0; d < 64; d++) col[(size_t)d * 1024] = 0;
        }
    } else {
        int r = (b & 255) * 256 + threadIdx.x;
        const uint4* p = (const uint4*)(Qh + (size_t)r * 64);
        u32 acc = 0;
        #pragma unroll
        for (int i = 0; i < 8; i++) {
            uint4 q = p[i];
            acc |= (q.x | q.y | q.z | q.w) & 0x7fff7fffu;
        }
        qm[r] = acc ? 1.f : 0.f;
    }
}

// ---------------------------------------------------------------------------
// Fused QKV projection GEMM, m97 structure: BM=BN=128, BK=32, 4 waves, 2-buf.
// 1-D grid 768, chunked XCD swizzle: XCD c owns 4 contiguous row-panels x
// all (sel,col) -> per-XCD working set = 1MB A + streamed W (4-way L2 reuse).
// ---------------------------------------------------------------------------
__launch_bounds__(256)
__global__ void gemm_qkv(const u16* __restrict__ A,
                         const u16* __restrict__ Wq, const u16* __restrict__ Wk,
                         const u16* __restrict__ Wv,
                         u16* __restrict__ Qh, u16* __restrict__ Kh, u16* __restrict__ Vt)
{
    __shared__ __align__(16) u16 lA[2][128 * 32];
    __shared__ __align__(16) u16 lB[2][128 * 32];
    const int tid = threadIdx.x, lane = tid & 63, w = tid >> 6;
    const int frow = lane & 15, koct = lane >> 4;
    const int id = blockIdx.x;
    const int tile = (id & 7) * 96 + (id >> 3);
    const int by = tile / 24;          // 0..31, contiguous per XCD chunk
    const int rem = tile % 24;
    const int sel = rem >> 3;
    const int col0 = (rem & 7) * 128, row0 = by * 128;
    const u16* B = (sel == 0) ? Wq : (sel == 1) ? Wk : Wv;
    const int wrow = (w >> 1) * 64, wcol = (w & 1) * 64;
    f32x4 acc[4][4] = {};

    auto stage = [&](int buf, int k0) {
        #pragma unroll
        for (int i = 0; i < 2; i++) {
            int p = tid + i * 256;
            int row = p >> 2, sl = p & 3, ssl = sl ^ ((row >> 1) & 3);
            gload16(A + (size_t)(row0 + row) * 1024 + k0 + ssl * 8, (char*)lA[buf] + p * 16);
        }
        #pragma unroll
        for (int i = 0; i < 2; i++) {
            int p = tid + i * 256;
            int row = p >> 2, sl = p & 3, ssl = sl ^ ((row >> 1) & 3);
            gload16(B + (size_t)(col0 + row) * 1024 + k0 + ssl * 8, (char*)lB[buf] + p * 16);
        }
    };

    stage(0, 0);
    __syncthreads();
    int buf = 0;
    for (int k0 = 0; k0 < 1024; k0 += 32) {
        if (k0 + 32 < 1024) stage(buf ^ 1, k0 + 32);
        __builtin_amdgcn_s_setprio(1);
        bf16x8 af[4], bf[4];
        #pragma unroll
        for (int i = 0; i < 4; i++) {
            int r = wrow + i * 16 + frow;
            int sl = koct ^ ((r >> 1) & 3);
            af[i] = *(const bf16x8*)((const char*)lA[buf] + r * 64 + sl * 16);
        }
        #pragma unroll
        for (int j = 0; j < 4; j++) {
            int r = wcol + j * 16 + frow;
            int sl = koct ^ ((r >> 1) & 3);
            bf[j] = *(const bf16x8*)((const char*)lB[buf] + r * 64 + sl * 16);
        }
        #pragma unroll
        for (int i = 0; i < 4; i++)
            #pragma unroll
            for (int j = 0; j < 4; j++)
                acc[i][j] = __builtin_amdgcn_mfma_f32_16x16x32_bf16(af[i], bf[j], acc[i][j], 0, 0, 0);
        __builtin_amdgcn_s_setprio(0);
        __syncthreads();
        buf ^= 1;
    }

    if (sel < 2) {
        const float scale = (sel == 0) ? 0.125f * LOG2E : 1.0f;
        u16* outp = (sel == 0) ? Qh : Kh;
        #pragma unroll
        for (int i = 0; i < 4; i++)
            #pragma unroll
            for (int j = 0; j < 4; j++)
                #pragma unroll
                for (int q = 0; q < 4; q++) {
                    int r = row0 + wrow + i * 16 + koct * 4 + q;
                    int c = col0 + wcol + j * 16 + frow;
                    float v = acc[i][j][q] * scale;
                    outp[(size_t)((c >> 6) * 4 + (r >> 10)) * 65536 +
                         (size_t)(r & 1023) * 64 + (c & 63)] = f2bf(v);
                }
    } else {
        #pragma unroll
        for (int i = 0; i < 4; i++) {
            int r0 = row0 + wrow + i * 16 + koct * 4;   // token base (mult of 4)
            #pragma unroll
            for (int j = 0; j < 4; j++) {
                int c = col0 + wcol + j * 16 + frow;    // channel
                int z = (c >> 6) * 4 + (r0 >> 10);
                uint2 pk;
                pk.x = cvt_pk_bf16(acc[i][j][0], acc[i][j][1]);
                pk.y = cvt_pk_bf16(acc[i][j][2], acc[i][j][3]);
                *(uint2*)(Vt + (size_t)z * 65536 + (size_t)(c & 63) * 1024 + (r0 & 1023)) = pk;
            }
        }
    }
}

// ---------------------------------------------------------------------------
// bf16 MFMA GEMM for FFN, 2-buf, XCD-swizzled tile map (T1).
// MODE 2: +bias+relu bf16. MODE 3: +bias bf16.
// ---------------------------------------------------------------------------
template <int MODE>
__launch_bounds__(256)
__global__ void gemm_bt(const u16* __restrict__ A, const u16* __restrict__ B,
                        const float* __restrict__ bias, u16* __restrict__ outp)
{
    __shared__ __align__(16) u16 lA[2][128 * 64];
    __shared__ __align__(16) u16 lB[2][64 * 64];
    const int tid = threadIdx.x, lane = tid & 63, w = tid >> 6;
    const int frow = lane & 15, koct = lane >> 4;
    const int id = blockIdx.x;                       // 1-D grid 512
    const int tile = (id & 7) * 64 + (id >> 3);
    const int col0 = (tile & 15) * 64, row0 = (tile >> 4) * 128;
    const int wrow = (w >> 1) * 64, wcol = (w & 1) * 32;
    f32x4 acc[4][2] = {};

    auto stage = [&](int buf, int k0) {
        #pragma unroll
        for (int i = 0; i < 4; i++) {
            int p = tid + i * 256;
            int row = p >> 3, sl = p & 7, ssl = sl ^ (row & 7);
            gload16(A + (size_t)(row0 + row) * 1024 + k0 + ssl * 8, (char*)lA[buf] + p * 16);
        }
        #pragma unroll
        for (int i = 0; i < 2; i++) {
            int p = tid + i * 256;
            int row = p >> 3, sl = p & 7, ssl = sl ^ (row & 7);
            gload16(B + (size_t)(col0 + row) * 1024 + k0 + ssl * 8, (char*)lB[buf] + p * 16);
        }
    };

    stage(0, 0);
    __syncthreads();
    int buf = 0;
    for (int k0 = 0; k0 < 1024; k0 += 64) {
        if (k0 + 64 < 1024) stage(buf ^ 1, k0 + 64);
        __builtin_amdgcn_s_setprio(1);
        #pragma unroll
        for (int ks = 0; ks < 2; ks++) {
            bf16x8 af[4], bf2[2];
            #pragma unroll
            for (int i = 0; i < 4; i++) {
                int r = wrow + i * 16 + frow;
                int sl = (ks * 4 + koct) ^ (r & 7);
                af[i] = *(const bf16x8*)((const char*)lA[buf] + r * 128 + sl * 16);
            }
            #pragma unroll
            for (int j = 0; j < 2; j++) {
                int r = wcol + j * 16 + frow;
                int sl = (ks * 4 + koct) ^ (r & 7);
                bf2[j] = *(const bf16x8*)((const char*)lB[buf] + r * 128 + sl * 16);
            }
            #pragma unroll
            for (int i = 0; i < 4; i++)
                #pragma unroll
                for (int j = 0; j < 2; j++)
                    acc[i][j] = __builtin_amdgcn_mfma_f32_16x16x32_bf16(af[i], bf2[j], acc[i][j], 0, 0, 0);
        }
        __builtin_amdgcn_s_setprio(0);
        __syncthreads();
        buf ^= 1;
    }

    #pragma unroll
    for (int i = 0; i < 4; i++)
        #pragma unroll
        for (int j = 0; j < 2; j++)
            #pragma unroll
            for (int q = 0; q < 4; q++) {
                int r = row0 + wrow + i * 16 + koct * 4 + q;
                int c = col0 + wcol + j * 16 + frow;
                float v = acc[i][j][q] + bias[c];
                if constexpr (MODE == 2) v = fmaxf(v, 0.f);
                outp[(size_t)r * 1024 + c] = f2bf(v);
            }
}

// ---------------------------------------------------------------------------
// Pass 1: partial[zg][n][m] = sum_{z in zg*16..+16} exp2(s'_znm) * km01(z,m)
// 1-D grid 1024, XCD-swizzled: XCD c owns one zg x 8 m-tiles.
// ---------------------------------------------------------------------------
__launch_bounds__(256)
__global__ void attn_pass1(const u16* __restrict__ Qh, const u16* __restrict__ Kh,
                           const float* __restrict__ km, float* __restrict__ partial)
{
    const int bid = blockIdx.x;
    const int mtzg = (bid & 7) * 8 + ((bid >> 3) & 7);   // cluster per XCD
    const int m0 = (mtzg & 15) * 64, zg = mtzg >> 4;
    const int n0 = (bid >> 6) * 64;

    __shared__ __align__(16) u16 lQ[2][64 * 64];
    __shared__ __align__(16) u16 lK[2][64 * 64];
    const int tid = threadIdx.x, lane = tid & 63, w = tid >> 6;
    const int frow = lane & 15, koct = lane >> 4;
    const int wn = (w >> 1) * 32, wm = (w & 1) * 32;
    f32x4 ssum[2][2] = {};

    auto stage = [&](int buf, int z) {
        #pragma unroll
        for (int i = 0; i < 2; i++) {
            int p = tid + i * 256;
            int row = p >> 3, sl = p & 7, ssl = sl ^ (row & 7);
            gload16(Qh + (size_t)(z * NSEQ + n0 + row) * 64 + ssl * 8, (char*)lQ[buf] + p * 16);
            gload16(Kh + (size_t)(z * NSEQ + m0 + row) * 64 + ssl * 8, (char*)lK[buf] + p * 16);
        }
    };

    const int z0 = zg * 16;
    stage(0, z0);
    __syncthreads();
    int buf = 0;
    for (int zi = 0; zi < 16; zi++) {
        const int z = z0 + zi;
        if (zi < 15) stage(buf ^ 1, z + 1);
        f32x4 km4[2];
        #pragma unroll
        for (int j = 0; j < 2; j++)
            km4[j] = *(const f32x4*)(km + z * NSEQ + m0 + wm + j * 16 + koct * 4);
        f32x4 s[2][2] = {};
        __builtin_amdgcn_s_setprio(1);
        #pragma unroll
        for (int ks = 0; ks < 2; ks++) {
            bf16x8 a[2], b2[2];
            #pragma unroll
            for (int i = 0; i < 2; i++) {
                int r = wn + i * 16 + frow;
                int sl = (ks * 4 + koct) ^ (r & 7);
                a[i] = *(const bf16x8*)((const char*)lQ[buf] + r * 128 + sl * 16);
            }
            #pragma unroll
            for (int j = 0; j < 2; j++) {
                int r = wm + j * 16 + frow;
                int sl = (ks * 4 + koct) ^ (r & 7);
                b2[j] = *(const bf16x8*)((const char*)lK[buf] + r * 128 + sl * 16);
            }
            #pragma unroll
            for (int i = 0; i < 2; i++)
                #pragma unroll
                for (int j = 0; j < 2; j++)
                    s[i][j] = __builtin_amdgcn_mfma_f32_16x16x32_bf16(b2[j], a[i], s[i][j], 0, 0, 0);
        }
        __builtin_amdgcn_s_setprio(0);
        #pragma unroll
        for (int j = 0; j < 2; j++)
            #pragma unroll
            for (int i = 0; i < 2; i++)
                #pragma unroll
                for (int q = 0; q < 4; q++)
                    ssum[i][j][q] += __builtin_amdgcn_exp2f(s[i][j][q]) * km4[j][q];
        __syncthreads();
        buf ^= 1;
    }
    #pragma unroll
    for (int i = 0; i < 2; i++)
        #pragma unroll
        for (int j = 0; j < 2; j++) {
            int ng = n0 + wn + i * 16 + frow;
            int mg = m0 + wm + j * 16 + koct * 4;
            *(f32x4*)(partial + (size_t)zg * 1048576 + (size_t)ng * NSEQ + mg) = ssum[i][j];
        }
}

// invS = 1 / (p0+p1+p2+p3)
__launch_bounds__(256)
__global__ void sum_inv(const float* __restrict__ p, float* __restrict__ invS) {
    int i = (blockIdx.x * 256 + threadIdx.x) * 4;
    float4 a = *(const float4*)(p + i);
    float4 b = *(const float4*)(p + 1048576 + i);
    float4 c = *(const float4*)(p + 2097152 + i);
    float4 d = *(const float4*)(p + 3145728 + i);
    float4 r;
    float s;
    s = a.x + b.x + c.x + d.x; r.x = s > 0.f ? 1.f / s : 0.f;
    s = a.y + b.y + c.y + d.y; r.y = s > 0.f ? 1.f / s : 0.f;
    s = a.z + b.z + c.z + d.z; r.z = s > 0.f ? 1.f / s : 0.f;
    s = a.w + b.w + c.w + d.w; r.w = s > 0.f ? 1.f / s : 0.f;
    *(float4*)(invS + i) = r;
}

// ---------------------------------------------------------------------------
// Pass 2 (R7 structure, bf16 output): per z, out = sum_m (exp2(s')*invS) V'[m,:]
// m-tile 64, double-buffered staging, wave-private lP, 1 barrier per tile.
// grid 1024, XCD c owns z in {8c..8c+7}.
// ---------------------------------------------------------------------------
__launch_bounds__(256)
__global__ void attn_pass2(const u16* __restrict__ Qh, const u16* __restrict__ Kh,
                           const u16* __restrict__ Vt,
                           const float* __restrict__ qm, const float* __restrict__ invS,
                           const u8* __restrict__ pad, u16* __restrict__ attn)
{
    const int bid = blockIdx.x;
    const int z  = (bid & 7) * 8 + ((bid >> 3) & 7);     // cluster per XCD
    const int n0 = (bid >> 6) * 64;

    __shared__ __align__(16) u16 lK[2][64 * 64];
    __shared__ __align__(16) u16 lV[2][64 * 64];   // Vt tile: [d][m]
    __shared__ __align__(16) u16 lP[64 * 64];
    const int tid = threadIdx.x, lane = tid & 63, w = tid >> 6;
    const int frow = lane & 15, koct = lane >> 4;
    const int hh = z >> 2, bb = z & 3;
    const int wrow = w * 16;
    const int nl_row = wrow + frow;
    const size_t inv_base = (size_t)(n0 + nl_row) * NSEQ;

    bf16x8 aq[2];
    #pragma unroll
    for (int ks = 0; ks < 2; ks++)
        aq[ks] = *(const bf16x8*)(Qh + (size_t)(z * NSEQ + n0 + nl_row) * 64 + ks * 32 + koct * 8);

    auto stage = [&](int buf, int m0) {
        #pragma unroll
        for (int i = 0; i < 2; i++) {
            int p = tid + i * 256;
            int row = p >> 3, sl = p & 7, ssl = sl ^ (row & 7);
            gload16(Kh + (size_t)(z * NSEQ + m0 + row) * 64 + ssl * 8, (char*)lK[buf] + p * 16);
            gload16(Vt + (size_t)z * 65536 + (size_t)row * 1024 + m0 + ssl * 8, (char*)lV[buf] + p * 16);
        }
    };

    f32x4 oacc[4] = {};
    f32x4 iv[4];
    #pragma unroll
    for (int j = 0; j < 4; j++)
        iv[j] = *(const f32x4*)(invS + inv_base + j * 16 + koct * 4);
    stage(0, 0);
    __syncthreads();
    int buf = 0;

    for (int mt = 0; mt < 16; mt++) {
        const int m0 = mt * 64;
        if (mt < 15) stage(buf ^ 1, m0 + 64);
        f32x4 ivn[4];
        if (mt < 15) {
            #pragma unroll
            for (int j = 0; j < 4; j++)
                ivn[j] = *(const f32x4*)(invS + inv_base + m0 + 64 + j * 16 + koct * 4);
        }
        f32x4 s[4] = {};
        __builtin_amdgcn_s_setprio(1);
        #pragma unroll
        for (int ks = 0; ks < 2; ks++) {
            bf16x8 kb[4];
            #pragma unroll
            for (int j = 0; j < 4; j++) {
                int r = j * 16 + frow;
                int sl = (ks * 4 + koct) ^ (r & 7);
                kb[j] = *(const bf16x8*)((const char*)lK[buf] + r * 128 + sl * 16);
            }
            #pragma unroll
            for (int j = 0; j < 4; j++)
                s[j] = __builtin_amdgcn_mfma_f32_16x16x32_bf16(kb[j], aq[ks], s[j], 0, 0, 0);
        }
        __builtin_amdgcn_s_setprio(0);
        #pragma unroll
        for (int j = 0; j < 4; j++) {
            float p0 = __builtin_amdgcn_exp2f(s[j][0]) * iv[j][0];
            float p1 = __builtin_amdgcn_exp2f(s[j][1]) * iv[j][1];
            float p2 = __builtin_amdgcn_exp2f(s[j][2]) * iv[j][2];
            float p3 = __builtin_amdgcn_exp2f(s[j][3]) * iv[j][3];
            uint2 pk;
            pk.x = cvt_pk_bf16(p0, p1);
            pk.y = cvt_pk_bf16(p2, p3);
            int slot = (j * 2 + (koct >> 1)) ^ (nl_row & 7);
            *(uint2*)((char*)lP + nl_row * 128 + slot * 16 + (koct & 1) * 8) = pk;
        }
        __builtin_amdgcn_s_setprio(1);
        #pragma unroll
        for (int ks = 0; ks < 2; ks++) {
            int sl = (ks * 4 + koct) ^ (nl_row & 7);
            bf16x8 pa = *(const bf16x8*)((const char*)lP + nl_row * 128 + sl * 16);
            bf16x8 vb[4];
            #pragma unroll
            for (int dj = 0; dj < 4; dj++) {
                int rr = dj * 16 + frow;
                int sv = (ks * 4 + koct) ^ (rr & 7);
                vb[dj] = *(const bf16x8*)((const char*)lV[buf] + rr * 128 + sv * 16);
            }
            #pragma unroll
            for (int dj = 0; dj < 4; dj++)
                oacc[dj] = __builtin_amdgcn_mfma_f32_16x16x32_bf16(pa, vb[dj], oacc[dj], 0, 0, 0);
        }
        __builtin_amdgcn_s_setprio(0);
        __syncthreads();
        buf ^= 1;
        #pragma unroll
        for (int j = 0; j < 4; j++) iv[j] = ivn[j];
    }

    #pragma unroll
    for (int q = 0; q < 4; q++) {
        int ns = n0 + wrow + koct * 4 + q;
        float f = qm[z * NSEQ + ns] * (pad[bb * NSEQ + ns] ? 0.f : 1.f);
        #pragma unroll
        for (int dj = 0; dj < 4; dj++) {
            int d = dj * 16 + frow;
            attn[(size_t)(bb * NSEQ + ns) * DMODEL + hh * 64 + d] = f2bf(oacc[dj][q] * f);
        }
    }
}

// ---------------------------------------------------------------------------
// LayerNorm over last dim (1024), one block per row.
// MODE 0: A bf16 + B bf16 -> v = a+b ; out bf16 (hb) only.
// MODE 1: A bf16, B bf16 -> v = a*valid + b ; out f32 * valid (final).
// ---------------------------------------------------------------------------
template <int MODE>
__launch_bounds__(256)
__global__ void ln_kernel(const u16* __restrict__ Ap, const u16* __restrict__ Bp,
                          const float* __restrict__ g, const float* __restrict__ beta,
                          const u8* __restrict__ pad,
                          float* __restrict__ outf, u16* __restrict__ outb)
{
    const int row = blockIdx.x, tid = threadIdx.x;
    const int lane = tid & 63, wv = tid >> 6;
    const float valid = pad[row] ? 0.f : 1.f;
    __shared__ float red[4];

    uint2 aav = *(const uint2*)(Ap + (size_t)row * 1024 + tid * 4);
    uint2 bbv = *(const uint2*)(Bp + (size_t)row * 1024 + tid * 4);
    float v[4];
    if constexpr (MODE == 0) {
        v[0] = bf2f(aav.x & 0xFFFFu) + bf2f(bbv.x & 0xFFFFu);
        v[1] = bf2f(aav.x >> 16)     + bf2f(bbv.x >> 16);
        v[2] = bf2f(aav.y & 0xFFFFu) + bf2f(bbv.y & 0xFFFFu);
        v[3] = bf2f(aav.y >> 16)     + bf2f(bbv.y >> 16);
    } else {
        v[0] = bf2f(aav.x & 0xFFFFu) * valid + bf2f(bbv.x & 0xFFFFu);
        v[1] = bf2f(aav.x >> 16)     * valid + bf2f(bbv.x >> 16);
        v[2] = bf2f(aav.y & 0xFFFFu) * valid + bf2f(bbv.y & 0xFFFFu);
        v[3] = bf2f(aav.y >> 16)     * valid + bf2f(bbv.y >> 16);
    }
    float s = v[0] + v[1] + v[2] + v[3];
    #pragma unroll
    for (int off = 32; off > 0; off >>= 1) s += __shfl_down(s, off, 64);
    if (lane == 0) red[wv] = s;
    __syncthreads();
    float mean = (red[0] + red[1] + red[2] + red[3]) * (1.f / 1024.f);
    float sq = 0.f;
    #pragma unroll
    for (int k = 0; k < 4; k++) { float d = v[k] - mean; sq += d * d; }
    __syncthreads();
    #pragma unroll
    for (int off = 32; off > 0; off >>= 1) sq += __shfl_down(sq, off, 64);
    if (lane == 0) red[wv] = sq;
    __syncthreads();
    float var = (red[0] + red[1] + red[2] + red[3]) * (1.f / 1024.f);
    float rstd = rsqrtf(var + 1e-5f);

    if constexpr (MODE == 0) {
        uint2 o;
        float o0 = (v[0] - mean) * rstd * g[tid * 4 + 0] + beta[tid * 4 + 0];
        float o1 = (v[1] - mean) * rstd * g[tid * 4 + 1] + beta[tid * 4 + 1];
        float o2 = (v[2] - mean) * rstd * g[tid * 4 + 2] + beta[tid * 4 + 2];
        float o3 = (v[3] - mean) * rstd * g[tid * 4 + 3] + beta[tid * 4 + 3];
        o.x = cvt_pk_bf16(o0, o1);
        o.y = cvt_pk_bf16(o2, o3);
        *(uint2*)(outb + (size_t)row * 1024 + tid * 4) = o;
    } else {
        float4 o;
        o.x = ((v[0] - mean) * rstd * g[tid * 4 + 0] + beta[tid * 4 + 0]) * valid;
        o.y = ((v[1] - mean) * rstd * g[tid * 4 + 1] + beta[tid * 4 + 1]) * valid;
        o.z = ((v[2] - mean) * rstd * g[tid * 4 + 2] + beta[tid * 4 + 2]) * valid;
        o.w = ((v[3] - mean) * rstd * g[tid * 4 + 3] + beta[tid * 4 + 3]) * valid;
        *(float4*)(outf + (size_t)row * 1024 + tid * 4) = o;
    }
}

// ---------------------------------------------------------------------------
extern "C" void kernel_launch(void* const* d_in, const int* in_sizes, int n_in,
                              void* d_out, int out_size, void* d_ws, size_t ws_size,
                              hipStream_t stream)
{
    const float* x   = (const float*)d_in[0];
    const u8*    pad = (const u8*)d_in[1];
    const float* Wq  = (const float*)d_in[2];
    const float* Wk  = (const float*)d_in[3];
    const float* Wv  = (const float*)d_in[4];
    const float* W1  = (const float*)d_in[5];
    const float* b1  = (const float*)d_in[6];
    const float* W2  = (const float*)d_in[7];
    const float* b2  = (const float*)d_in[8];
    const float* g1  = (const float*)d_in[9];
    const float* be1 = (const float*)d_in[10];
    const float* g2  = (const float*)d_in[11];
    const float* be2 = (const float*)d_in[12];
    float* out = (float*)d_out;

    // workspace (~95 MB)
    u16* xb    = (u16*)d_ws;
    u16* Wqb   = xb    + 4194304;
    u16* Wkb   = Wqb   + 1048576;
    u16* Wvb   = Wkb   + 1048576;
    u16* W1b   = Wvb   + 1048576;
    u16* W2b   = W1b   + 1048576;
    u16* Qh    = W2b   + 1048576;        // [z][n][dh]
    u16* Kh    = Qh    + 4194304;        // [z][n][dh]
    u16* Vt    = Kh    + 4194304;        // [z][dh][n]  (km applied in rowmask_fused)
    u16* hb    = Vt    + 4194304;        // LN1 output, bf16
    u16* ff1b  = hb    + 4194304;
    u16* ffb   = ff1b  + 4194304;        // FFN2 output, bf16
    u16* attnb = ffb   + 4194304;        // attention output, bf16
    float* km      = (float*)(attnb + 4194304);
    float* qm      = km      + 65536;
    float* partial = qm      + 65536;           // 4M f32
    float* invS    = partial + 4194304;         // 1M f32

    P5 p5;
    p5.in[0] = Wq; p5.in[1] = Wk; p5.in[2] = Wv; p5.in[3] = W1; p5.in[4] = W2;
    p5.out[0] = Wqb; p5.out[1] = Wkb; p5.out[2] = Wvb; p5.out[3] = W1b; p5.out[4] = W2b;
    cvt_all<<<9216, 256, 0, stream>>>(x, xb, p5);

    // fused Q/K/V projections, chunked XCD swizzle (1-D grid 768)
    gemm_qkv<<<768, 256, 0, stream>>>(xb, Wqb, Wkb, Wvb, Qh, Kh, Vt);

    // km/qm masks + rare-path V masking (replaces rowmask2 + vt_km)
    rowmask_fused<<<512, 256, 0, stream>>>(Kh, Qh, Vt, km, qm);

    attn_pass1<<<1024, 256, 0, stream>>>(Qh, Kh, km, partial);
    sum_inv<<<1024, 256, 0, stream>>>(partial, invS);
    attn_pass2<<<1024, 256, 0, stream>>>(Qh, Kh, Vt, qm, invS, pad, attnb);

    // h = LN(xb + attn) -> bf16 only
    ln_kernel<0><<<4096, 256, 0, stream>>>(xb, attnb, g1, be1, pad, nullptr, hb);

    // FFN (both outputs bf16, XCD-swizzled 1-D grids)
    gemm_bt<2><<<512, 256, 0, stream>>>(hb,   W1b, b1, ff1b);
    gemm_bt<3><<<512, 256, 0, stream>>>(ff1b, W2b, b2, ffb);

    // out = LN(ff*valid + h) * valid  (final f32)
    ln_kernel<1><<<4096, 256, 0, stream>>>(ffb, hb, g2, be2, pad, out, nullptr);
}

// Round 19
// 167.167 us; speedup vs baseline: 1.1810x; 1.0074x over previous
//
#include <hip/hip_runtime.h>
#include <math.h>

typedef unsigned short u16;
typedef unsigned char  u8;
typedef unsigned int   u32;
typedef __attribute__((ext_vector_type(8))) short bf16x8;
typedef __attribute__((ext_vector_type(4))) float f32x4;

#define NSEQ   1024
#define DMODEL 1024
#define ZTOT   64
#define LOG2E  1.4426950408889634f

typedef const __attribute__((address_space(1))) void* gp1;
typedef __attribute__((address_space(3))) void* lp3;

__device__ __forceinline__ void gload16(const void* g, void* l) {
    __builtin_amdgcn_global_load_lds((gp1)g, (lp3)l, 16, 0, 0);
}

__device__ __forceinline__ u16 f2bf(float f) {
    u32 u = __builtin_bit_cast(u32, f);
    return (u16)((u + 0x7FFFu + ((u >> 16) & 1u)) >> 16);
}

__device__ __forceinline__ float bf2f(u32 lo16) {
    u32 t = lo16 << 16;
    return __builtin_bit_cast(float, t);
}

// HW packed f32->bf16 (RNE), 2 values -> 1 dword
__device__ __forceinline__ u32 cvt_pk_bf16(float a, float b) {
    u32 r;
    asm("v_cvt_pk_bf16_f32 %0, %1, %2" : "=v"(r) : "v"(a), "v"(b));
    return r;
}

// ---------------------------------------------------------------------------
// fp32 -> bf16 elementwise: x (4M elems) + 5 weights (1M each) in ONE launch.
// ---------------------------------------------------------------------------
struct P5 { const float* in[5]; u16* out[5]; };
__launch_bounds__(256)
__global__ void cvt_all(const float* __restrict__ x, u16* __restrict__ xb, P5 p) {
    int bid = blockIdx.x;
    const float* in;
    u16* out;
    int blk;
    if (bid < 4096) { in = x; out = xb; blk = bid; }
    else {
        int which = (bid - 4096) >> 10;
        blk = bid & 1023;
        in = p.in[which];
        out = p.out[which];
    }
    int i = (blk * 256 + threadIdx.x) * 4;
    float4 v = *(const float4*)(in + i);
    uint2 o;
    o.x = cvt_pk_bf16(v.x, v.y);
    o.y = cvt_pk_bf16(v.z, v.w);
    *(uint2*)(out + i) = o;
}

// ---------------------------------------------------------------------------
// Fused masks: blocks 0..255: km = sign(sum|Kh row|), and zero Vt[z][:,tok]
// where km == 0 (rare path, exec-mask skipped when no lane triggers).
// Blocks 256..511: qm from Qh.
// ---------------------------------------------------------------------------
__launch_bounds__(256)
__global__ void rowmask_fused(const u16* __restrict__ Kh, const u16* __restrict__ Qh,
                              u16* __restrict__ Vt,
                              float* __restrict__ km, float* __restrict__ qm) {
    int b = blockIdx.x;
    if (b < 256) {
        int r = b * 256 + threadIdx.x;          // r = z*1024 + tok
        const uint4* p = (const uint4*)(Kh + (size_t)r * 64);
        u32 acc = 0;
        #pragma unroll
        for (int i = 0; i < 8; i++) {
            uint4 q = p[i];
            acc |= (q.x | q.y | q.z | q.w) & 0x7fff7fffu;
        }
        km[r] = acc ? 1.f : 0.f;
        if (!acc) {                             // km==0: zero V column (rare)
            int z = r >> 10, tok = r & 1023;
            u16* col = Vt + (size_t)z * 65536 + tok;
            #pragma unroll
            for (int d = 0; d < 64; d++) col[(size_t)d * 1024] = 0;
        }
    } else {
        int r = (b & 255) * 256 + threadIdx.x;
        const uint4* p = (const uint4*)(Qh + (size_t)r * 64);
        u32 acc = 0;
        #pragma unroll
        for (int i = 0; i < 8; i++) {
            uint4 q = p[i];
            acc |= (q.x | q.y | q.z | q.w) & 0x7fff7fffu;
        }
        qm[r] = acc ? 1.f : 0.f;
    }
}

// ---------------------------------------------------------------------------
// Fused QKV projection GEMM, m97 structure: BM=BN=128, BK=32, 4 waves, 2-buf.
// 1-D grid 768, chunked XCD swizzle.
// ---------------------------------------------------------------------------
__launch_bounds__(256)
__global__ void gemm_qkv(const u16* __restrict__ A,
                         const u16* __restrict__ Wq, const u16* __restrict__ Wk,
                         const u16* __restrict__ Wv,
                         u16* __restrict__ Qh, u16* __restrict__ Kh, u16* __restrict__ Vt)
{
    __shared__ __align__(16) u16 lA[2][128 * 32];
    __shared__ __align__(16) u16 lB[2][128 * 32];
    const int tid = threadIdx.x, lane = tid & 63, w = tid >> 6;
    const int frow = lane & 15, koct = lane >> 4;
    const int id = blockIdx.x;
    const int tile = (id & 7) * 96 + (id >> 3);
    const int by = tile / 24;          // 0..31, contiguous per XCD chunk
    const int rem = tile % 24;
    const int sel = rem >> 3;
    const int col0 = (rem & 7) * 128, row0 = by * 128;
    const u16* B = (sel == 0) ? Wq : (sel == 1) ? Wk : Wv;
    const int wrow = (w >> 1) * 64, wcol = (w & 1) * 64;
    f32x4 acc[4][4] = {};

    auto stage = [&](int buf, int k0) {
        #pragma unroll
        for (int i = 0; i < 2; i++) {
            int p = tid + i * 256;
            int row = p >> 2, sl = p & 3, ssl = sl ^ ((row >> 1) & 3);
            gload16(A + (size_t)(row0 + row) * 1024 + k0 + ssl * 8, (char*)lA[buf] + p * 16);
        }
        #pragma unroll
        for (int i = 0; i < 2; i++) {
            int p = tid + i * 256;
            int row = p >> 2, sl = p & 3, ssl = sl ^ ((row >> 1) & 3);
            gload16(B + (size_t)(col0 + row) * 1024 + k0 + ssl * 8, (char*)lB[buf] + p * 16);
        }
    };

    stage(0, 0);
    __syncthreads();
    int buf = 0;
    for (int k0 = 0; k0 < 1024; k0 += 32) {
        if (k0 + 32 < 1024) stage(buf ^ 1, k0 + 32);
        __builtin_amdgcn_s_setprio(1);
        bf16x8 af[4], bf[4];
        #pragma unroll
        for (int i = 0; i < 4; i++) {
            int r = wrow + i * 16 + frow;
            int sl = koct ^ ((r >> 1) & 3);
            af[i] = *(const bf16x8*)((const char*)lA[buf] + r * 64 + sl * 16);
        }
        #pragma unroll
        for (int j = 0; j < 4; j++) {
            int r = wcol + j * 16 + frow;
            int sl = koct ^ ((r >> 1) & 3);
            bf[j] = *(const bf16x8*)((const char*)lB[buf] + r * 64 + sl * 16);
        }
        #pragma unroll
        for (int i = 0; i < 4; i++)
            #pragma unroll
            for (int j = 0; j < 4; j++)
                acc[i][j] = __builtin_amdgcn_mfma_f32_16x16x32_bf16(af[i], bf[j], acc[i][j], 0, 0, 0);
        __builtin_amdgcn_s_setprio(0);
        __syncthreads();
        buf ^= 1;
    }

    if (sel < 2) {
        const float scale = (sel == 0) ? 0.125f * LOG2E : 1.0f;
        u16* outp = (sel == 0) ? Qh : Kh;
        #pragma unroll
        for (int i = 0; i < 4; i++)
            #pragma unroll
            for (int j = 0; j < 4; j++)
                #pragma unroll
                for (int q = 0; q < 4; q++) {
                    int r = row0 + wrow + i * 16 + koct * 4 + q;
                    int c = col0 + wcol + j * 16 + frow;
                    float v = acc[i][j][q] * scale;
                    outp[(size_t)((c >> 6) * 4 + (r >> 10)) * 65536 +
                         (size_t)(r & 1023) * 64 + (c & 63)] = f2bf(v);
                }
    } else {
        #pragma unroll
        for (int i = 0; i < 4; i++) {
            int r0 = row0 + wrow + i * 16 + koct * 4;   // token base (mult of 4)
            #pragma unroll
            for (int j = 0; j < 4; j++) {
                int c = col0 + wcol + j * 16 + frow;    // channel
                int z = (c >> 6) * 4 + (r0 >> 10);
                uint2 pk;
                pk.x = cvt_pk_bf16(acc[i][j][0], acc[i][j][1]);
                pk.y = cvt_pk_bf16(acc[i][j][2], acc[i][j][3]);
                *(uint2*)(Vt + (size_t)z * 65536 + (size_t)(c & 63) * 1024 + (r0 & 1023)) = pk;
            }
        }
    }
}

// ---------------------------------------------------------------------------
// bf16 MFMA GEMM for FFN, 2-buf, XCD-swizzled tile map (T1).
// MODE 2: +bias+relu bf16. MODE 3: +bias bf16.
// ---------------------------------------------------------------------------
template <int MODE>
__launch_bounds__(256)
__global__ void gemm_bt(const u16* __restrict__ A, const u16* __restrict__ B,
                        const float* __restrict__ bias, u16* __restrict__ outp)
{
    __shared__ __align__(16) u16 lA[2][128 * 64];
    __shared__ __align__(16) u16 lB[2][64 * 64];
    const int tid = threadIdx.x, lane = tid & 63, w = tid >> 6;
    const int frow = lane & 15, koct = lane >> 4;
    const int id = blockIdx.x;                       // 1-D grid 512
    const int tile = (id & 7) * 64 + (id >> 3);
    const int col0 = (tile & 15) * 64, row0 = (tile >> 4) * 128;
    const int wrow = (w >> 1) * 64, wcol = (w & 1) * 32;
    f32x4 acc[4][2] = {};

    auto stage = [&](int buf, int k0) {
        #pragma unroll
        for (int i = 0; i < 4; i++) {
            int p = tid + i * 256;
            int row = p >> 3, sl = p & 7, ssl = sl ^ (row & 7);
            gload16(A + (size_t)(row0 + row) * 1024 + k0 + ssl * 8, (char*)lA[buf] + p * 16);
        }
        #pragma unroll
        for (int i = 0; i < 2; i++) {
            int p = tid + i * 256;
            int row = p >> 3, sl = p & 7, ssl = sl ^ (row & 7);
            gload16(B + (size_t)(col0 + row) * 1024 + k0 + ssl * 8, (char*)lB[buf] + p * 16);
        }
    };

    stage(0, 0);
    __syncthreads();
    int buf = 0;
    for (int k0 = 0; k0 < 1024; k0 += 64) {
        if (k0 + 64 < 1024) stage(buf ^ 1, k0 + 64);
        __builtin_amdgcn_s_setprio(1);
        #pragma unroll
        for (int ks = 0; ks < 2; ks++) {
            bf16x8 af[4], bf2[2];
            #pragma unroll
            for (int i = 0; i < 4; i++) {
                int r = wrow + i * 16 + frow;
                int sl = (ks * 4 + koct) ^ (r & 7);
                af[i] = *(const bf16x8*)((const char*)lA[buf] + r * 128 + sl * 16);
            }
            #pragma unroll
            for (int j = 0; j < 2; j++) {
                int r = wcol + j * 16 + frow;
                int sl = (ks * 4 + koct) ^ (r & 7);
                bf2[j] = *(const bf16x8*)((const char*)lB[buf] + r * 128 + sl * 16);
            }
            #pragma unroll
            for (int i = 0; i < 4; i++)
                #pragma unroll
                for (int j = 0; j < 2; j++)
                    acc[i][j] = __builtin_amdgcn_mfma_f32_16x16x32_bf16(af[i], bf2[j], acc[i][j], 0, 0, 0);
        }
        __builtin_amdgcn_s_setprio(0);
        __syncthreads();
        buf ^= 1;
    }

    #pragma unroll
    for (int i = 0; i < 4; i++)
        #pragma unroll
        for (int j = 0; j < 2; j++)
            #pragma unroll
            for (int q = 0; q < 4; q++) {
                int r = row0 + wrow + i * 16 + koct * 4 + q;
                int c = col0 + wcol + j * 16 + frow;
                float v = acc[i][j][q] + bias[c];
                if constexpr (MODE == 2) v = fmaxf(v, 0.f);
                outp[(size_t)r * 1024 + c] = f2bf(v);
            }
}

// ---------------------------------------------------------------------------
// Pass 1: partial[zg][n][m] = sum_{z in zg*16..+16} exp2(s'_znm) * km01(z,m)
// bf16 partial output (halves write traffic). 1-D grid 1024, XCD-swizzled.
// ---------------------------------------------------------------------------
__launch_bounds__(256)
__global__ void attn_pass1(const u16* __restrict__ Qh, const u16* __restrict__ Kh,
                           const float* __restrict__ km, u16* __restrict__ partial)
{
    const int bid = blockIdx.x;
    const int mtzg = (bid & 7) * 8 + ((bid >> 3) & 7);   // cluster per XCD
    const int m0 = (mtzg & 15) * 64, zg = mtzg >> 4;
    const int n0 = (bid >> 6) * 64;

    __shared__ __align__(16) u16 lQ[2][64 * 64];
    __shared__ __align__(16) u16 lK[2][64 * 64];
    const int tid = threadIdx.x, lane = tid & 63, w = tid >> 6;
    const int frow = lane & 15, koct = lane >> 4;
    const int wn = (w >> 1) * 32, wm = (w & 1) * 32;
    f32x4 ssum[2][2] = {};

    auto stage = [&](int buf, int z) {
        #pragma unroll
        for (int i = 0; i < 2; i++) {
            int p = tid + i * 256;
            int row = p >> 3, sl = p & 7, ssl = sl ^ (row & 7);
            gload16(Qh + (size_t)(z * NSEQ + n0 + row) * 64 + ssl * 8, (char*)lQ[buf] + p * 16);
            gload16(Kh + (size_t)(z * NSEQ + m0 + row) * 64 + ssl * 8, (char*)lK[buf] + p * 16);
        }
    };

    const int z0 = zg * 16;
    stage(0, z0);
    __syncthreads();
    int buf = 0;
    for (int zi = 0; zi < 16; zi++) {
        const int z = z0 + zi;
        if (zi < 15) stage(buf ^ 1, z + 1);
        f32x4 km4[2];
        #pragma unroll
        for (int j = 0; j < 2; j++)
            km4[j] = *(const f32x4*)(km + z * NSEQ + m0 + wm + j * 16 + koct * 4);
        f32x4 s[2][2] = {};
        __builtin_amdgcn_s_setprio(1);
        #pragma unroll
        for (int ks = 0; ks < 2; ks++) {
            bf16x8 a[2], b2[2];
            #pragma unroll
            for (int i = 0; i < 2; i++) {
                int r = wn + i * 16 + frow;
                int sl = (ks * 4 + koct) ^ (r & 7);
                a[i] = *(const bf16x8*)((const char*)lQ[buf] + r * 128 + sl * 16);
            }
            #pragma unroll
            for (int j = 0; j < 2; j++) {
                int r = wm + j * 16 + frow;
                int sl = (ks * 4 + koct) ^ (r & 7);
                b2[j] = *(const bf16x8*)((const char*)lK[buf] + r * 128 + sl * 16);
            }
            #pragma unroll
            for (int i = 0; i < 2; i++)
                #pragma unroll
                for (int j = 0; j < 2; j++)
                    s[i][j] = __builtin_amdgcn_mfma_f32_16x16x32_bf16(b2[j], a[i], s[i][j], 0, 0, 0);
        }
        __builtin_amdgcn_s_setprio(0);
        #pragma unroll
        for (int j = 0; j < 2; j++)
            #pragma unroll
            for (int i = 0; i < 2; i++)
                #pragma unroll
                for (int q = 0; q < 4; q++)
                    ssum[i][j][q] += __builtin_amdgcn_exp2f(s[i][j][q]) * km4[j][q];
        __syncthreads();
        buf ^= 1;
    }
    #pragma unroll
    for (int i = 0; i < 2; i++)
        #pragma unroll
        for (int j = 0; j < 2; j++) {
            int ng = n0 + wn + i * 16 + frow;
            int mg = m0 + wm + j * 16 + koct * 4;
            uint2 pk;
            pk.x = cvt_pk_bf16(ssum[i][j][0], ssum[i][j][1]);
            pk.y = cvt_pk_bf16(ssum[i][j][2], ssum[i][j][3]);
            *(uint2*)(partial + (size_t)zg * 1048576 + (size_t)ng * NSEQ + mg) = pk;
        }
}

// invS = 1 / (p0+p1+p2+p3)   (bf16 partials -> f32 invS)
__launch_bounds__(256)
__global__ void sum_inv(const u16* __restrict__ p, float* __restrict__ invS) {
    int i = (blockIdx.x * 256 + threadIdx.x) * 4;
    uint2 a = *(const uint2*)(p + i);
    uint2 b = *(const uint2*)(p + 1048576 + i);
    uint2 c = *(const uint2*)(p + 2097152 + i);
    uint2 d = *(const uint2*)(p + 3145728 + i);
    float4 r;
    float s;
    s = bf2f(a.x & 0xFFFFu) + bf2f(b.x & 0xFFFFu) + bf2f(c.x & 0xFFFFu) + bf2f(d.x & 0xFFFFu);
    r.x = s > 0.f ? 1.f / s : 0.f;
    s = bf2f(a.x >> 16) + bf2f(b.x >> 16) + bf2f(c.x >> 16) + bf2f(d.x >> 16);
    r.y = s > 0.f ? 1.f / s : 0.f;
    s = bf2f(a.y & 0xFFFFu) + bf2f(b.y & 0xFFFFu) + bf2f(c.y & 0xFFFFu) + bf2f(d.y & 0xFFFFu);
    r.z = s > 0.f ? 1.f / s : 0.f;
    s = bf2f(a.y >> 16) + bf2f(b.y >> 16) + bf2f(c.y >> 16) + bf2f(d.y >> 16);
    r.w = s > 0.f ? 1.f / s : 0.f;
    *(float4*)(invS + i) = r;
}

// ---------------------------------------------------------------------------
// Pass 2 (R7 structure, bf16 output): per z, out = sum_m (exp2(s')*invS) V'[m,:]
// m-tile 64, double-buffered staging, wave-private lP, 1 barrier per tile.
// grid 1024, XCD c owns z in {8c..8c+7}.
// ---------------------------------------------------------------------------
__launch_bounds__(256)
__global__ void attn_pass2(const u16* __restrict__ Qh, const u16* __restrict__ Kh,
                           const u16* __restrict__ Vt,
                           const float* __restrict__ qm, const float* __restrict__ invS,
                           const u8* __restrict__ pad, u16* __restrict__ attn)
{
    const int bid = blockIdx.x;
    const int z  = (bid & 7) * 8 + ((bid >> 3) & 7);     // cluster per XCD
    const int n0 = (bid >> 6) * 64;

    __shared__ __align__(16) u16 lK[2][64 * 64];
    __shared__ __align__(16) u16 lV[2][64 * 64];   // Vt tile: [d][m]
    __shared__ __align__(16) u16 lP[64 * 64];
    const int tid = threadIdx.x, lane = tid & 63, w = tid >> 6;
    const int frow = lane & 15, koct = lane >> 4;
    const int hh = z >> 2, bb = z & 3;
    const int wrow = w * 16;
    const int nl_row = wrow + frow;
    const size_t inv_base = (size_t)(n0 + nl_row) * NSEQ;

    bf16x8 aq[2];
    #pragma unroll
    for (int ks = 0; ks < 2; ks++)
        aq[ks] = *(const bf16x8*)(Qh + (size_t)(z * NSEQ + n0 + nl_row) * 64 + ks * 32 + koct * 8);

    auto stage = [&](int buf, int m0) {
        #pragma unroll
        for (int i = 0; i < 2; i++) {
            int p = tid + i * 256;
            int row = p >> 3, sl = p & 7, ssl = sl ^ (row & 7);
            gload16(Kh + (size_t)(z * NSEQ + m0 + row) * 64 + ssl * 8, (char*)lK[buf] + p * 16);
            gload16(Vt + (size_t)z * 65536 + (size_t)row * 1024 + m0 + ssl * 8, (char*)lV[buf] + p * 16);
        }
    };

    f32x4 oacc[4] = {};
    f32x4 iv[4];
    #pragma unroll
    for (int j = 0; j < 4; j++)
        iv[j] = *(const f32x4*)(invS + inv_base + j * 16 + koct * 4);
    stage(0, 0);
    __syncthreads();
    int buf = 0;

    for (int mt = 0; mt < 16; mt++) {
        const int m0 = mt * 64;
        if (mt < 15) stage(buf ^ 1, m0 + 64);
        f32x4 ivn[4];
        if (mt < 15) {
            #pragma unroll
            for (int j = 0; j < 4; j++)
                ivn[j] = *(const f32x4*)(invS + inv_base + m0 + 64 + j * 16 + koct * 4);
        }
        f32x4 s[4] = {};
        __builtin_amdgcn_s_setprio(1);
        #pragma unroll
        for (int ks = 0; ks < 2; ks++) {
            bf16x8 kb[4];
            #pragma unroll
            for (int j = 0; j < 4; j++) {
                int r = j * 16 + frow;
                int sl = (ks * 4 + koct) ^ (r & 7);
                kb[j] = *(const bf16x8*)((const char*)lK[buf] + r * 128 + sl * 16);
            }
            #pragma unroll
            for (int j = 0; j < 4; j++)
                s[j] = __builtin_amdgcn_mfma_f32_16x16x32_bf16(kb[j], aq[ks], s[j], 0, 0, 0);
        }
        __builtin_amdgcn_s_setprio(0);
        #pragma unroll
        for (int j = 0; j < 4; j++) {
            float p0 = __builtin_amdgcn_exp2f(s[j][0]) * iv[j][0];
            float p1 = __builtin_amdgcn_exp2f(s[j][1]) * iv[j][1];
            float p2 = __builtin_amdgcn_exp2f(s[j][2]) * iv[j][2];
            float p3 = __builtin_amdgcn_exp2f(s[j][3]) * iv[j][3];
            uint2 pk;
            pk.x = cvt_pk_bf16(p0, p1);
            pk.y = cvt_pk_bf16(p2, p3);
            int slot = (j * 2 + (koct >> 1)) ^ (nl_row & 7);
            *(uint2*)((char*)lP + nl_row * 128 + slot * 16 + (koct & 1) * 8) = pk;
        }
        __builtin_amdgcn_s_setprio(1);
        #pragma unroll
        for (int ks = 0; ks < 2; ks++) {
            int sl = (ks * 4 + koct) ^ (nl_row & 7);
            bf16x8 pa = *(const bf16x8*)((const char*)lP + nl_row * 128 + sl * 16);
            bf16x8 vb[4];
            #pragma unroll
            for (int dj = 0; dj < 4; dj++) {
                int rr = dj * 16 + frow;
                int sv = (ks * 4 + koct) ^ (rr & 7);
                vb[dj] = *(const bf16x8*)((const char*)lV[buf] + rr * 128 + sv * 16);
            }
            #pragma unroll
            for (int dj = 0; dj < 4; dj++)
                oacc[dj] = __builtin_amdgcn_mfma_f32_16x16x32_bf16(pa, vb[dj], oacc[dj], 0, 0, 0);
        }
        __builtin_amdgcn_s_setprio(0);
        __syncthreads();
        buf ^= 1;
        #pragma unroll
        for (int j = 0; j < 4; j++) iv[j] = ivn[j];
    }

    #pragma unroll
    for (int q = 0; q < 4; q++) {
        int ns = n0 + wrow + koct * 4 + q;
        float f = qm[z * NSEQ + ns] * (pad[bb * NSEQ + ns] ? 0.f : 1.f);
        #pragma unroll
        for (int dj = 0; dj < 4; dj++) {
            int d = dj * 16 + frow;
            attn[(size_t)(bb * NSEQ + ns) * DMODEL + hh * 64 + d] = f2bf(oacc[dj][q] * f);
        }
    }
}

// ---------------------------------------------------------------------------
// LayerNorm over last dim (1024), one block per row.
// MODE 0: A bf16 + B bf16 -> v = a+b ; out bf16 (hb) only.
// MODE 1: A bf16, B bf16 -> v = a*valid + b ; out f32 * valid (final).
// ---------------------------------------------------------------------------
template <int MODE>
__launch_bounds__(256)
__global__ void ln_kernel(const u16* __restrict__ Ap, const u16* __restrict__ Bp,
                          const float* __restrict__ g, const float* __restrict__ beta,
                          const u8* __restrict__ pad,
                          float* __restrict__ outf, u16* __restrict__ outb)
{
    const int row = blockIdx.x, tid = threadIdx.x;
    const int lane = tid & 63, wv = tid >> 6;
    const float valid = pad[row] ? 0.f : 1.f;
    __shared__ float red[4];

    uint2 aav = *(const uint2*)(Ap + (size_t)row * 1024 + tid * 4);
    uint2 bbv = *(const uint2*)(Bp + (size_t)row * 1024 + tid * 4);
    float v[4];
    if constexpr (MODE == 0) {
        v[0] = bf2f(aav.x & 0xFFFFu) + bf2f(bbv.x & 0xFFFFu);
        v[1] = bf2f(aav.x >> 16)     + bf2f(bbv.x >> 16);
        v[2] = bf2f(aav.y & 0xFFFFu) + bf2f(bbv.y & 0xFFFFu);
        v[3] = bf2f(aav.y >> 16)     + bf2f(bbv.y >> 16);
    } else {
        v[0] = bf2f(aav.x & 0xFFFFu) * valid + bf2f(bbv.x & 0xFFFFu);
        v[1] = bf2f(aav.x >> 16)     * valid + bf2f(bbv.x >> 16);
        v[2] = bf2f(aav.y & 0xFFFFu) * valid + bf2f(bbv.y & 0xFFFFu);
        v[3] = bf2f(aav.y >> 16)     * valid + bf2f(bbv.y >> 16);
    }
    float s = v[0] + v[1] + v[2] + v[3];
    #pragma unroll
    for (int off = 32; off > 0; off >>= 1) s += __shfl_down(s, off, 64);
    if (lane == 0) red[wv] = s;
    __syncthreads();
    float mean = (red[0] + red[1] + red[2] + red[3]) * (1.f / 1024.f);
    float sq = 0.f;
    #pragma unroll
    for (int k = 0; k < 4; k++) { float d = v[k] - mean; sq += d * d; }
    __syncthreads();
    #pragma unroll
    for (int off = 32; off > 0; off >>= 1) sq += __shfl_down(sq, off, 64);
    if (lane == 0) red[wv] = sq;
    __syncthreads();
    float var = (red[0] + red[1] + red[2] + red[3]) * (1.f / 1024.f);
    float rstd = rsqrtf(var + 1e-5f);

    if constexpr (MODE == 0) {
        uint2 o;
        float o0 = (v[0] - mean) * rstd * g[tid * 4 + 0] + beta[tid * 4 + 0];
        float o1 = (v[1] - mean) * rstd * g[tid * 4 + 1] + beta[tid * 4 + 1];
        float o2 = (v[2] - mean) * rstd * g[tid * 4 + 2] + beta[tid * 4 + 2];
        float o3 = (v[3] - mean) * rstd * g[tid * 4 + 3] + beta[tid * 4 + 3];
        o.x = cvt_pk_bf16(o0, o1);
        o.y = cvt_pk_bf16(o2, o3);
        *(uint2*)(outb + (size_t)row * 1024 + tid * 4) = o;
    } else {
        float4 o;
        o.x = ((v[0] - mean) * rstd * g[tid * 4 + 0] + beta[tid * 4 + 0]) * valid;
        o.y = ((v[1] - mean) * rstd * g[tid * 4 + 1] + beta[tid * 4 + 1]) * valid;
        o.z = ((v[2] - mean) * rstd * g[tid * 4 + 2] + beta[tid * 4 + 2]) * valid;
        o.w = ((v[3] - mean) * rstd * g[tid * 4 + 3] + beta[tid * 4 + 3]) * valid;
        *(float4*)(outf + (size_t)row * 1024 + tid * 4) = o;
    }
}

// ---------------------------------------------------------------------------
extern "C" void kernel_launch(void* const* d_in, const int* in_sizes, int n_in,
                              void* d_out, int out_size, void* d_ws, size_t ws_size,
                              hipStream_t stream)
{
    const float* x   = (const float*)d_in[0];
    const u8*    pad = (const u8*)d_in[1];
    const float* Wq  = (const float*)d_in[2];
    const float* Wk  = (const float*)d_in[3];
    const float* Wv  = (const float*)d_in[4];
    const float* W1  = (const float*)d_in[5];
    const float* b1  = (const float*)d_in[6];
    const float* W2  = (const float*)d_in[7];
    const float* b2  = (const float*)d_in[8];
    const float* g1  = (const float*)d_in[9];
    const float* be1 = (const float*)d_in[10];
    const float* g2  = (const float*)d_in[11];
    const float* be2 = (const float*)d_in[12];
    float* out = (float*)d_out;

    // workspace (~90 MB)
    u16* xb    = (u16*)d_ws;
    u16* Wqb   = xb    + 4194304;
    u16* Wkb   = Wqb   + 1048576;
    u16* Wvb   = Wkb   + 1048576;
    u16* W1b   = Wvb   + 1048576;
    u16* W2b   = W1b   + 1048576;
    u16* Qh    = W2b   + 1048576;        // [z][n][dh]
    u16* Kh    = Qh    + 4194304;        // [z][n][dh]
    u16* Vt    = Kh    + 4194304;        // [z][dh][n]  (km applied in rowmask_fused)
    u16* hb    = Vt    + 4194304;        // LN1 output, bf16
    u16* ff1b  = hb    + 4194304;
    u16* ffb   = ff1b  + 4194304;        // FFN2 output, bf16
    u16* attnb = ffb   + 4194304;        // attention output, bf16
    u16* partial = attnb + 4194304;      // 4 slabs x 1M bf16 (8 MB)
    float* km    = (float*)(partial + 4194304);
    float* qm    = km + 65536;
    float* invS  = qm + 65536;           // 1M f32

    P5 p5;
    p5.in[0] = Wq; p5.in[1] = Wk; p5.in[2] = Wv; p5.in[3] = W1; p5.in[4] = W2;
    p5.out[0] = Wqb; p5.out[1] = Wkb; p5.out[2] = Wvb; p5.out[3] = W1b; p5.out[4] = W2b;
    cvt_all<<<9216, 256, 0, stream>>>(x, xb, p5);

    // fused Q/K/V projections, chunked XCD swizzle (1-D grid 768)
    gemm_qkv<<<768, 256, 0, stream>>>(xb, Wqb, Wkb, Wvb, Qh, Kh, Vt);

    // km/qm masks + rare-path V masking
    rowmask_fused<<<512, 256, 0, stream>>>(Kh, Qh, Vt, km, qm);

    attn_pass1<<<1024, 256, 0, stream>>>(Qh, Kh, km, partial);
    sum_inv<<<1024, 256, 0, stream>>>(partial, invS);
    attn_pass2<<<1024, 256, 0, stream>>>(Qh, Kh, Vt, qm, invS, pad, attnb);

    // h = LN(xb + attn) -> bf16 only
    ln_kernel<0><<<4096, 256, 0, stream>>>(xb, attnb, g1, be1, pad, nullptr, hb);

    // FFN (both outputs bf16, XCD-swizzled 1-D grids)
    gemm_bt<2><<<512, 256, 0, stream>>>(hb,   W1b, b1, ff1b);
    gemm_bt<3><<<512, 256, 0, stream>>>(ff1b, W2b, b2, ffb);

    // out = LN(ff*valid + h) * valid  (final f32)
    ln_kernel<1><<<4096, 256, 0, stream>>>(ffb, hb, g2, be2, pad, out, nullptr);
}